// Round 1
// baseline (653.537 us; speedup 1.0000x reference)
//
#include <hip/hip_runtime.h>
#include <hip/hip_bf16.h>

#define DEV static __device__ __forceinline__

typedef __attribute__((ext_vector_type(4))) float f32x4;
typedef __attribute__((ext_vector_type(8))) short bf16x8;

DEV unsigned short f2bf(float x){
  __hip_bfloat16 h = __float2bfloat16(x);
  return __builtin_bit_cast(unsigned short, h);
}
DEV float softplus_f(float x){ return fmaxf(x, 0.f) + log1pf(expf(-fabsf(x))); }

DEV void gload16(const void* g, void* l){
  __builtin_amdgcn_global_load_lds((const __attribute__((address_space(1))) void*)g,
                                   (__attribute__((address_space(3))) void*)l, 16, 0, 0);
}

// ---------------------------------------------------------------------------
// Transpose + fp32->bf16: in[K][N] f32 -> out[N][K] bf16.  grid(N/32, K/32), 256 thr.
__global__ void k_transpose(const float* __restrict__ in, unsigned short* __restrict__ out,
                            int K, int N){
  __shared__ float t[32][33];
  const int nt = blockIdx.x * 32, kt = blockIdx.y * 32;
  const int r  = threadIdx.x >> 3;
  const int c4 = (threadIdx.x & 7) * 4;
  const float4 v = *(const float4*)(in + (size_t)(kt + r) * N + nt + c4);
  t[r][c4+0] = v.x; t[r][c4+1] = v.y; t[r][c4+2] = v.z; t[r][c4+3] = v.w;
  __syncthreads();
  ushort4 o;
  o.x = f2bf(t[c4+0][r]); o.y = f2bf(t[c4+1][r]);
  o.z = f2bf(t[c4+2][r]); o.w = f2bf(t[c4+3][r]);
  *(ushort4*)(out + (size_t)(nt + r) * K + kt + c4) = o;
}

// Gather emb[x] -> bf16 [4096][512].  grid(4096), 128 thr.
__global__ void k_gather(const int* __restrict__ x, const float* __restrict__ emb,
                         unsigned short* __restrict__ eA){
  const int t = blockIdx.x;
  const int idx = x[t];
  const float4 v = ((const float4*)(emb + (size_t)idx * 512))[threadIdx.x];
  ushort4 o; o.x = f2bf(v.x); o.y = f2bf(v.y); o.z = f2bf(v.z); o.w = f2bf(v.w);
  ((ushort4*)(eA + (size_t)t * 512))[threadIdx.x] = o;
}

// act[b,s,:] = bf16(tanh(G[b,s]+H[b,s+1]+b_f1)), act[b,2047,:]=0.  grid(4096), 128 thr.
__global__ void k_ew1(const float* __restrict__ GH, const float* __restrict__ b1,
                      unsigned short* __restrict__ act){
  const int blk = blockIdx.x;
  const int s = blk & 2047;
  const int d = threadIdx.x * 4;
  ushort4 o;
  if (s == 2047){ o.x = o.y = o.z = o.w = 0; }
  else {
    const float4 g  = *(const float4*)(GH + (size_t)blk * 1024 + d);
    const float4 h  = *(const float4*)(GH + (size_t)(blk + 1) * 1024 + 512 + d);
    const float4 bb = *(const float4*)(b1 + d);
    o.x = f2bf(tanhf(g.x + h.x + bb.x));
    o.y = f2bf(tanhf(g.y + h.y + bb.y));
    o.z = f2bf(tanhf(g.z + h.z + bb.z));
    o.w = f2bf(tanhf(g.w + h.w + bb.w));
  }
  *(ushort4*)(act + (size_t)blk * 512 + d) = o;
}

// m = max(m + dt*(F[s-1]-F[s]), eps), zero-flux boundaries.  grid(4096), 128 thr.
__global__ void k_update(const float* __restrict__ F, const float* __restrict__ cfl,
                         float* __restrict__ m32, unsigned short* __restrict__ m16){
  const int blk = blockIdx.x;
  const int s = blk & 2047;
  const int d = threadIdx.x * 4;
  const float dt = 1.f / (1.f + expf(-cfl[0]));
  float4 fp = make_float4(0.f,0.f,0.f,0.f), fc = make_float4(0.f,0.f,0.f,0.f);
  if (s > 0)    fp = *(const float4*)(F + (size_t)(blk - 1) * 512 + d);
  if (s < 2047) fc = *(const float4*)(F + (size_t)blk * 512 + d);
  float4 mv = *(const float4*)(m32 + (size_t)blk * 512 + d);
  mv.x = fmaxf(mv.x + dt * (fp.x - fc.x), 1e-6f);
  mv.y = fmaxf(mv.y + dt * (fp.y - fc.y), 1e-6f);
  mv.z = fmaxf(mv.z + dt * (fp.z - fc.z), 1e-6f);
  mv.w = fmaxf(mv.w + dt * (fp.w - fc.w), 1e-6f);
  *(float4*)(m32 + (size_t)blk * 512 + d) = mv;
  ushort4 o; o.x = f2bf(mv.x); o.y = f2bf(mv.y); o.z = f2bf(mv.z); o.w = f2bf(mv.w);
  *(ushort4*)(m16 + (size_t)blk * 512 + d) = o;
}

// ---------------------------------------------------------------------------
// C[M,N] = A[M,K] @ Bt[N,K]^T, bf16 in / f32 acc.  128x128 tile, BK=64, 4 waves.
// EPI: 0 raw, 1 softplus(x+bias)+eps -> f32+bf16, 2 softplus(x+bias) -> f32, 3 x+bias -> f32
template<int EPI>
__global__ __launch_bounds__(256, 2)
void gemm128(const unsigned short* __restrict__ A, const unsigned short* __restrict__ Bt,
             const float* __restrict__ bias, float* __restrict__ outF,
             unsigned short* __restrict__ outBf, int K, int N)
{
  __shared__ unsigned short lA[128 * 64];
  __shared__ unsigned short lB[128 * 64];
  const int tid  = threadIdx.x;
  const int lane = tid & 63;
  const int w    = tid >> 6;       // wave 0..3
  const int wr   = w >> 1, wc = w & 1;
  const int rowA0 = blockIdx.x * 128;
  const int rowB0 = blockIdx.y * 128;

  f32x4 acc[4][4];
  const f32x4 z = {0.f, 0.f, 0.f, 0.f};
  #pragma unroll
  for (int i = 0; i < 4; i++)
    #pragma unroll
    for (int j = 0; j < 4; j++) acc[i][j] = z;

  const int subr = lane >> 3;      // 0..7 row-within-subtile
  const int cc   = lane & 7;       // 16B chunk index

  for (int k0 = 0; k0 < K; k0 += 64){
    __syncthreads();
    #pragma unroll
    for (int i = 0; i < 4; i++){
      const int sub = w * 4 + i;               // 0..15, 8 rows each
      const int r   = sub * 8 + subr;          // 0..127
      const int cs  = cc ^ (r & 7);            // inverse-swizzled source chunk
      gload16(A  + (size_t)(rowA0 + r) * K + k0 + cs * 8, &lA[sub * 512]);
      gload16(Bt + (size_t)(rowB0 + r) * K + k0 + cs * 8, &lB[sub * 512]);
    }
    __syncthreads();
    #pragma unroll
    for (int ks = 0; ks < 2; ks++){
      bf16x8 af[4], bfr[4];
      #pragma unroll
      for (int i = 0; i < 4; i++){
        const int ra = wr * 64 + i * 16 + (lane & 15);
        const int ka = (ks * 4 + (lane >> 4)) ^ (ra & 7);   // swizzled read chunk
        af[i] = *(const bf16x8*)&lA[ra * 64 + ka * 8];
        const int rb = wc * 64 + i * 16 + (lane & 15);
        const int kb = (ks * 4 + (lane >> 4)) ^ (rb & 7);
        bfr[i] = *(const bf16x8*)&lB[rb * 64 + kb * 8];
      }
      #pragma unroll
      for (int i = 0; i < 4; i++)
        #pragma unroll
        for (int j = 0; j < 4; j++)
          acc[i][j] = __builtin_amdgcn_mfma_f32_16x16x32_bf16(af[i], bfr[j], acc[i][j], 0, 0, 0);
    }
  }

  // epilogue: D row = (lane>>4)*4 + reg, col = lane&15  (per 16x16 fragment)
  const int r4 = (lane >> 4) * 4;
  const int cl = lane & 15;
  #pragma unroll
  for (int j = 0; j < 4; j++){
    const int col = rowB0 + wc * 64 + j * 16 + cl;
    const float bv = (EPI != 0) ? bias[col] : 0.f;
    #pragma unroll
    for (int i = 0; i < 4; i++){
      const int row0 = rowA0 + wr * 64 + i * 16 + r4;
      #pragma unroll
      for (int r = 0; r < 4; r++){
        float v = acc[i][j][r];
        if (EPI == 1)      v = softplus_f(v + bv) + 1e-6f;
        else if (EPI == 2) v = softplus_f(v + bv);
        else if (EPI == 3) v = v + bv;
        const size_t o = (size_t)(row0 + r) * N + col;
        outF[o] = v;
        if (EPI == 1) outBf[o] = f2bf(v);
      }
    }
  }
}

// ---------------------------------------------------------------------------
extern "C" void kernel_launch(void* const* d_in, const int* in_sizes, int n_in,
                              void* d_out, int out_size, void* d_ws, size_t ws_size,
                              hipStream_t stream) {
  const int*   x      = (const int*)  d_in[0];
  const float* emb    = (const float*)d_in[1];
  const float* w_mass = (const float*)d_in[2];
  const float* b_mass = (const float*)d_in[3];
  const float* w_f1   = (const float*)d_in[4];
  const float* b_f1   = (const float*)d_in[5];
  const float* w_f2   = (const float*)d_in[6];
  const float* b_f2   = (const float*)d_in[7];
  const float* cfl    = (const float*)d_in[8];
  const float* w_dec  = (const float*)d_in[9];
  const float* b_dec  = (const float*)d_in[10];
  float* out = (float*)d_out;

  char* ws = (char*)d_ws;
  size_t off = 0;
  auto alloc = [&](size_t bytes) -> void* {
    void* p = ws + off;
    off += (bytes + 255) & ~(size_t)255;
    return p;
  };
  unsigned short* wTdec  = (unsigned short*)alloc((size_t)32000 * 512 * 2);
  unsigned short* eA     = (unsigned short*)alloc((size_t)4096 * 512 * 2);
  unsigned short* wTmass = (unsigned short*)alloc((size_t)512 * 512 * 2);
  unsigned short* wTf1   = (unsigned short*)alloc((size_t)1024 * 512 * 2);
  unsigned short* wTf2   = (unsigned short*)alloc((size_t)512 * 512 * 2);
  float*          m32    = (float*)         alloc((size_t)4096 * 512 * 4);
  unsigned short* m16    = (unsigned short*)alloc((size_t)4096 * 512 * 2);
  float*          GH     = (float*)         alloc((size_t)4096 * 1024 * 4);
  unsigned short* act    = (unsigned short*)alloc((size_t)4096 * 512 * 2);
  float*          Fbuf   = (float*)         alloc((size_t)4096 * 512 * 4);

  const dim3 b256(256);
  // weight prep (every call; kernel_launch must be deterministic/stateless)
  k_transpose<<<dim3(16, 16),   b256, 0, stream>>>(w_mass,            wTmass,            512, 512);
  k_transpose<<<dim3(16, 16),   b256, 0, stream>>>(w_f1,              wTf1,              512, 512);
  k_transpose<<<dim3(16, 16),   b256, 0, stream>>>(w_f1 + 512 * 512,  wTf1 + 512 * 512,  512, 512);
  k_transpose<<<dim3(16, 16),   b256, 0, stream>>>(w_f2,              wTf2,              512, 512);
  k_transpose<<<dim3(1000, 16), b256, 0, stream>>>(w_dec,             wTdec,             512, 32000);
  k_gather<<<4096, 128, 0, stream>>>(x, emb, eA);

  // m = softplus(e @ w_mass + b_mass) + eps
  gemm128<1><<<dim3(32, 4), b256, 0, stream>>>(eA, wTmass, b_mass, m32, m16, 512, 512);

  for (int it = 0; it < 3; ++it){
    // [G|H] = m @ [w_f1_top | w_f1_bot]   -> [4096, 1024] f32
    gemm128<0><<<dim3(32, 8), b256, 0, stream>>>(m16, wTf1, nullptr, GH, nullptr, 512, 1024);
    k_ew1<<<4096, 128, 0, stream>>>(GH, b_f1, act);
    // F = softplus(act @ w_f2 + b_f2)     -> [4096, 512] f32 (row s=2047 garbage, ignored)
    gemm128<2><<<dim3(32, 4), b256, 0, stream>>>(act, wTf2, b_f2, Fbuf, nullptr, 512, 512);
    k_update<<<4096, 128, 0, stream>>>(Fbuf, cfl, m32, m16);
  }

  // logits = m @ w_dec + b_dec  -> [4096, 32000] f32
  gemm128<3><<<dim3(32, 250), b256, 0, stream>>>(m16, wTdec, b_dec, out, nullptr, 512, 32000);
}

// Round 2
// 456.702 us; speedup vs baseline: 1.4310x; 1.4310x over previous
//
#include <hip/hip_runtime.h>
#include <hip/hip_bf16.h>

#define DEV static __device__ __forceinline__

typedef __attribute__((ext_vector_type(4))) float f32x4;
typedef __attribute__((ext_vector_type(8))) short bf16x8;

DEV unsigned short f2bf(float x){
  __hip_bfloat16 h = __float2bfloat16(x);
  return __builtin_bit_cast(unsigned short, h);
}
DEV float b2f(unsigned short u){
  __hip_bfloat16 h = __builtin_bit_cast(__hip_bfloat16, u);
  return __bfloat162float(h);
}
DEV float softplus_f(float x){ return fmaxf(x, 0.f) + log1pf(expf(-fabsf(x))); }

DEV void gload16(const void* g, void* l){
  __builtin_amdgcn_global_load_lds((const __attribute__((address_space(1))) void*)g,
                                   (__attribute__((address_space(3))) void*)l, 16, 0, 0);
}

// ---------------------------------------------------------------------------
// Transpose + fp32->bf16: in[K][N] f32 -> out[N][K] bf16.
__global__ void k_transpose(const float* __restrict__ in, unsigned short* __restrict__ out,
                            int K, int N){
  __shared__ float t[32][33];
  const int nt = blockIdx.x * 32, kt = blockIdx.y * 32;
  const int r  = threadIdx.x >> 3;
  const int c4 = (threadIdx.x & 7) * 4;
  const float4 v = *(const float4*)(in + (size_t)(kt + r) * N + nt + c4);
  t[r][c4+0] = v.x; t[r][c4+1] = v.y; t[r][c4+2] = v.z; t[r][c4+3] = v.w;
  __syncthreads();
  ushort4 o;
  o.x = f2bf(t[c4+0][r]); o.y = f2bf(t[c4+1][r]);
  o.z = f2bf(t[c4+2][r]); o.w = f2bf(t[c4+3][r]);
  *(ushort4*)(out + (size_t)(nt + r) * K + kt + c4) = o;
}

// Fused 512x512 transposes: z=0 w_mass, z=1 w_f1[:512], z=2 w_f1[512:], z=3 w_f2.
__global__ void k_transpose4(const float* __restrict__ w_mass, const float* __restrict__ w_f1,
                             const float* __restrict__ w_f2, unsigned short* __restrict__ wTmass,
                             unsigned short* __restrict__ wTf1, unsigned short* __restrict__ wTf2){
  __shared__ float t[32][33];
  const float* in; unsigned short* out;
  switch (blockIdx.z){
    case 0:  in = w_mass;            out = wTmass;            break;
    case 1:  in = w_f1;              out = wTf1;              break;
    case 2:  in = w_f1 + 512 * 512;  out = wTf1 + 512 * 512;  break;
    default: in = w_f2;              out = wTf2;              break;
  }
  const int nt = blockIdx.x * 32, kt = blockIdx.y * 32;
  const int r  = threadIdx.x >> 3;
  const int c4 = (threadIdx.x & 7) * 4;
  const float4 v = *(const float4*)(in + (size_t)(kt + r) * 512 + nt + c4);
  t[r][c4+0] = v.x; t[r][c4+1] = v.y; t[r][c4+2] = v.z; t[r][c4+3] = v.w;
  __syncthreads();
  ushort4 o;
  o.x = f2bf(t[c4+0][r]); o.y = f2bf(t[c4+1][r]);
  o.z = f2bf(t[c4+2][r]); o.w = f2bf(t[c4+3][r]);
  *(ushort4*)(out + (size_t)(nt + r) * 512 + kt + c4) = o;
}

// Gather emb[x] -> bf16 [4096][512].
__global__ void k_gather(const int* __restrict__ x, const float* __restrict__ emb,
                         unsigned short* __restrict__ eA){
  const int t = blockIdx.x;
  const int idx = x[t];
  const float4 v = ((const float4*)(emb + (size_t)idx * 512))[threadIdx.x];
  ushort4 o; o.x = f2bf(v.x); o.y = f2bf(v.y); o.z = f2bf(v.z); o.w = f2bf(v.w);
  ((ushort4*)(eA + (size_t)t * 512))[threadIdx.x] = o;
}

// act[b,s,:] = bf16(tanh(G[b,s]+H[b,s+1]+b_f1)), act[b,2047,:]=0.  GH is bf16 [4096][1024].
__global__ void k_ew1(const unsigned short* __restrict__ GH, const float* __restrict__ b1,
                      unsigned short* __restrict__ act){
  const int blk = blockIdx.x;
  const int s = blk & 2047;
  const int d = threadIdx.x * 4;
  ushort4 o;
  if (s == 2047){ o.x = o.y = o.z = o.w = 0; }
  else {
    const ushort4 g  = *(const ushort4*)(GH + (size_t)blk * 1024 + d);
    const ushort4 h  = *(const ushort4*)(GH + (size_t)(blk + 1) * 1024 + 512 + d);
    const float4 bb = *(const float4*)(b1 + d);
    o.x = f2bf(tanhf(b2f(g.x) + b2f(h.x) + bb.x));
    o.y = f2bf(tanhf(b2f(g.y) + b2f(h.y) + bb.y));
    o.z = f2bf(tanhf(b2f(g.z) + b2f(h.z) + bb.z));
    o.w = f2bf(tanhf(b2f(g.w) + b2f(h.w) + bb.w));
  }
  *(ushort4*)(act + (size_t)blk * 512 + d) = o;
}

// m = max(m + dt*(F[s-1]-F[s]), eps), zero-flux boundaries.
__global__ void k_update(const float* __restrict__ F, const float* __restrict__ cfl,
                         float* __restrict__ m32, unsigned short* __restrict__ m16){
  const int blk = blockIdx.x;
  const int s = blk & 2047;
  const int d = threadIdx.x * 4;
  const float dt = 1.f / (1.f + expf(-cfl[0]));
  float4 fp = make_float4(0.f,0.f,0.f,0.f), fc = make_float4(0.f,0.f,0.f,0.f);
  if (s > 0)    fp = *(const float4*)(F + (size_t)(blk - 1) * 512 + d);
  if (s < 2047) fc = *(const float4*)(F + (size_t)blk * 512 + d);
  float4 mv = *(const float4*)(m32 + (size_t)blk * 512 + d);
  mv.x = fmaxf(mv.x + dt * (fp.x - fc.x), 1e-6f);
  mv.y = fmaxf(mv.y + dt * (fp.y - fc.y), 1e-6f);
  mv.z = fmaxf(mv.z + dt * (fp.z - fc.z), 1e-6f);
  mv.w = fmaxf(mv.w + dt * (fp.w - fc.w), 1e-6f);
  *(float4*)(m32 + (size_t)blk * 512 + d) = mv;
  ushort4 o; o.x = f2bf(mv.x); o.y = f2bf(mv.y); o.z = f2bf(mv.z); o.w = f2bf(mv.w);
  *(ushort4*)(m16 + (size_t)blk * 512 + d) = o;
}

// ---------------------------------------------------------------------------
// Small GEMM: C[M,N] = A[M,K] @ Bt[N,K]^T, 4 waves (2x2), BMxBN tile, BK=64.
// EPI: 1 softplus(x+bias)+eps -> f32 outF + bf16 outBf, 2 softplus(x+bias) -> f32,
//      4 raw x -> bf16 outBf.
template<int BM, int BN, int EPI>
__global__ __launch_bounds__(256, 2)
void gemmT(const unsigned short* __restrict__ A, const unsigned short* __restrict__ Bt,
           const float* __restrict__ bias, float* __restrict__ outF,
           unsigned short* __restrict__ outBf, int K, int N)
{
  __shared__ unsigned short lA[BM * 64];
  __shared__ unsigned short lB[BN * 64];
  constexpr int NA = BM / 32;   // A gload ops per wave; also A-frag count per wave
  constexpr int NB = BN / 32;   // B gload ops per wave; also B-frag count per wave
  const int tid  = threadIdx.x;
  const int lane = tid & 63;
  const int w    = tid >> 6;
  const int wr   = w >> 1, wc = w & 1;
  const int rowA0 = blockIdx.x * BM;
  const int rowB0 = blockIdx.y * BN;

  f32x4 acc[NA][NB];
  const f32x4 z = {0.f, 0.f, 0.f, 0.f};
  #pragma unroll
  for (int i = 0; i < NA; i++)
    #pragma unroll
    for (int j = 0; j < NB; j++) acc[i][j] = z;

  const int subr = lane >> 3;
  const int cc   = lane & 7;

  for (int k0 = 0; k0 < K; k0 += 64){
    __syncthreads();
    #pragma unroll
    for (int i = 0; i < NA; i++){
      const int sub = w * NA + i;
      const int r   = sub * 8 + subr;
      const int cs  = cc ^ (r & 7);
      gload16(A + (size_t)(rowA0 + r) * K + k0 + cs * 8, &lA[sub * 512]);
    }
    #pragma unroll
    for (int i = 0; i < NB; i++){
      const int sub = w * NB + i;
      const int r   = sub * 8 + subr;
      const int cs  = cc ^ (r & 7);
      gload16(Bt + (size_t)(rowB0 + r) * K + k0 + cs * 8, &lB[sub * 512]);
    }
    __syncthreads();
    #pragma unroll
    for (int ks = 0; ks < 2; ks++){
      bf16x8 af[NA], bfr[NB];
      #pragma unroll
      for (int i = 0; i < NA; i++){
        const int ra = wr * (BM / 2) + i * 16 + (lane & 15);
        const int ka = (ks * 4 + (lane >> 4)) ^ (ra & 7);
        af[i] = *(const bf16x8*)&lA[ra * 64 + ka * 8];
      }
      #pragma unroll
      for (int j = 0; j < NB; j++){
        const int rb = wc * (BN / 2) + j * 16 + (lane & 15);
        const int kb = (ks * 4 + (lane >> 4)) ^ (rb & 7);
        bfr[j] = *(const bf16x8*)&lB[rb * 64 + kb * 8];
      }
      #pragma unroll
      for (int i = 0; i < NA; i++)
        #pragma unroll
        for (int j = 0; j < NB; j++)
          acc[i][j] = __builtin_amdgcn_mfma_f32_16x16x32_bf16(af[i], bfr[j], acc[i][j], 0, 0, 0);
    }
  }

  const int r4 = (lane >> 4) * 4;
  const int cl = lane & 15;
  #pragma unroll
  for (int j = 0; j < NB; j++){
    const int col = rowB0 + wc * (BN / 2) + j * 16 + cl;
    const float bv = (EPI == 1 || EPI == 2) ? bias[col] : 0.f;
    #pragma unroll
    for (int i = 0; i < NA; i++){
      const int row0 = rowA0 + wr * (BM / 2) + i * 16 + r4;
      #pragma unroll
      for (int r = 0; r < 4; r++){
        float v = acc[i][j][r];
        if (EPI == 1)      v = softplus_f(v + bv) + 1e-6f;
        else if (EPI == 2) v = softplus_f(v + bv);
        const size_t o = (size_t)(row0 + r) * N + col;
        if (EPI == 4){
          outBf[o] = f2bf(v);
        } else {
          outF[o] = v;
          if (EPI == 1) outBf[o] = f2bf(v);
        }
      }
    }
  }
}

// ---------------------------------------------------------------------------
// Big GEMM (decoder): 256x256 tile, BK=64, 8 waves (2Mx4N), dbuf LDS 128 KiB,
// counted vmcnt pipeline (prefetch depth 2 K-tiles, never drains to 0 mid-loop).
// C = A[M,K] @ Bt[N,K]^T + bias, f32 out.  Requires K/64 >= 2, grid 1D = nbx*nby,
// dynamic LDS = 131072 B.
__global__ __launch_bounds__(512, 2)
void gemm256(const unsigned short* __restrict__ A, const unsigned short* __restrict__ Bt,
             const float* __restrict__ bias, float* __restrict__ out,
             int K, int N, int nbx)
{
  extern __shared__ unsigned short lds[];   // [2][A:16384 | B:16384]
  const int tid  = threadIdx.x;
  const int lane = tid & 63;
  const int w    = tid >> 6;        // 0..7
  const int wr   = w >> 2;          // 0..1
  const int wc   = w & 3;           // 0..3

  // bijective XCD-chunked swizzle (gridDim.x % 8 == 0): same-N-tile blocks colocate.
  const int nwg = gridDim.x;
  const int cpx = nwg >> 3;
  const int swz = (blockIdx.x & 7) * cpx + (blockIdx.x >> 3);
  const int rowA0 = (swz % nbx) * 256;
  const int rowB0 = (swz / nbx) * 256;

  const int subr = lane >> 3;
  const int cc   = lane & 7;

  auto stage = [&](int kt, int buf){
    unsigned short* la = lds + buf * 32768;
    unsigned short* lb = la + 16384;
    const int k0 = kt * 64;
    #pragma unroll
    for (int i = 0; i < 4; i++){
      const int sub = w * 4 + i;           // 0..31
      const int r   = sub * 8 + subr;      // 0..255
      const int cs  = cc ^ (r & 7);
      gload16(A  + (size_t)(rowA0 + r) * K + k0 + cs * 8, la + sub * 512);
      gload16(Bt + (size_t)(rowB0 + r) * K + k0 + cs * 8, lb + sub * 512);
    }
  };

  f32x4 acc[8][4];
  const f32x4 z = {0.f, 0.f, 0.f, 0.f};
  #pragma unroll
  for (int i = 0; i < 8; i++)
    #pragma unroll
    for (int j = 0; j < 4; j++) acc[i][j] = z;

  const int nt = K >> 6;
  // prologue: stage tiles 0 and 1; wait for tile 0 (8 newest loads may remain).
  stage(0, 0);
  stage(1, 1);
  asm volatile("s_waitcnt vmcnt(8)" ::: "memory");
  __builtin_amdgcn_s_barrier();
  __builtin_amdgcn_sched_barrier(0);

  for (int t = 0; t < nt; ++t){
    const int cur = t & 1;
    const unsigned short* la = lds + cur * 32768;
    const unsigned short* lb = la + 16384;

    #pragma unroll
    for (int ks = 0; ks < 2; ks++){
      bf16x8 af[8], bfr[4];
      #pragma unroll
      for (int i = 0; i < 8; i++){
        const int ra = wr * 128 + i * 16 + (lane & 15);
        const int ka = (ks * 4 + (lane >> 4)) ^ (ra & 7);
        af[i] = *(const bf16x8*)(la + ra * 64 + ka * 8);
      }
      #pragma unroll
      for (int j = 0; j < 4; j++){
        const int rb = wc * 64 + j * 16 + (lane & 15);
        const int kb = (ks * 4 + (lane >> 4)) ^ (rb & 7);
        bfr[j] = *(const bf16x8*)(lb + rb * 64 + kb * 8);
      }
      if (ks == 1){
        // all of this wave's reads of buf[cur] retired, then block-wide barrier:
        // safe to overwrite buf[cur] with tile t+2.
        asm volatile("s_waitcnt lgkmcnt(0)" ::: "memory");
        __builtin_amdgcn_sched_barrier(0);
        __builtin_amdgcn_s_barrier();
        __builtin_amdgcn_sched_barrier(0);
        if (t + 2 < nt) stage(t + 2, cur);
      }
      __builtin_amdgcn_s_setprio(1);
      #pragma unroll
      for (int i = 0; i < 8; i++)
        #pragma unroll
        for (int j = 0; j < 4; j++)
          acc[i][j] = __builtin_amdgcn_mfma_f32_16x16x32_bf16(af[i], bfr[j], acc[i][j], 0, 0, 0);
      __builtin_amdgcn_s_setprio(0);
    }

    if (t < nt - 1){
      // guarantee tile t+1 landed (per-wave: own 8 loads for t+2 may stay in flight;
      // barrier extends the guarantee to all waves' loads).
      if (t + 2 < nt) asm volatile("s_waitcnt vmcnt(8)" ::: "memory");
      else            asm volatile("s_waitcnt vmcnt(0)" ::: "memory");
      __builtin_amdgcn_s_barrier();
      __builtin_amdgcn_sched_barrier(0);
    }
  }

  const int r4 = (lane >> 4) * 4;
  const int cl = lane & 15;
  #pragma unroll
  for (int j = 0; j < 4; j++){
    const int col = rowB0 + wc * 64 + j * 16 + cl;
    const float bv = bias[col];
    #pragma unroll
    for (int i = 0; i < 8; i++){
      const int row0 = rowA0 + wr * 128 + i * 16 + r4;
      #pragma unroll
      for (int r = 0; r < 4; r++)
        out[(size_t)(row0 + r) * N + col] = acc[i][j][r] + bv;
    }
  }
}

// ---------------------------------------------------------------------------
extern "C" void kernel_launch(void* const* d_in, const int* in_sizes, int n_in,
                              void* d_out, int out_size, void* d_ws, size_t ws_size,
                              hipStream_t stream) {
  const int*   x      = (const int*)  d_in[0];
  const float* emb    = (const float*)d_in[1];
  const float* w_mass = (const float*)d_in[2];
  const float* b_mass = (const float*)d_in[3];
  const float* w_f1   = (const float*)d_in[4];
  const float* b_f1   = (const float*)d_in[5];
  const float* w_f2   = (const float*)d_in[6];
  const float* b_f2   = (const float*)d_in[7];
  const float* cfl    = (const float*)d_in[8];
  const float* w_dec  = (const float*)d_in[9];
  const float* b_dec  = (const float*)d_in[10];
  float* out = (float*)d_out;

  char* ws = (char*)d_ws;
  size_t off = 0;
  auto alloc = [&](size_t bytes) -> void* {
    void* p = ws + off;
    off += (bytes + 255) & ~(size_t)255;
    return p;
  };
  unsigned short* wTdec  = (unsigned short*)alloc((size_t)32000 * 512 * 2);
  unsigned short* eA     = (unsigned short*)alloc((size_t)4096 * 512 * 2);
  unsigned short* wTmass = (unsigned short*)alloc((size_t)512 * 512 * 2);
  unsigned short* wTf1   = (unsigned short*)alloc((size_t)1024 * 512 * 2);
  unsigned short* wTf2   = (unsigned short*)alloc((size_t)512 * 512 * 2);
  float*          m32    = (float*)         alloc((size_t)4096 * 512 * 4);
  unsigned short* m16    = (unsigned short*)alloc((size_t)4096 * 512 * 2);
  unsigned short* GHb    = (unsigned short*)alloc((size_t)4096 * 1024 * 2);
  unsigned short* act    = (unsigned short*)alloc((size_t)4096 * 512 * 2);
  float*          Fbuf   = (float*)         alloc((size_t)4096 * 512 * 4);

  hipFuncSetAttribute(reinterpret_cast<const void*>(&gemm256),
                      hipFuncAttributeMaxDynamicSharedMemorySize, 131072);

  const dim3 b256(256);
  k_transpose4<<<dim3(16, 16, 4), b256, 0, stream>>>(w_mass, w_f1, w_f2, wTmass, wTf1, wTf2);
  k_transpose<<<dim3(1000, 16), b256, 0, stream>>>(w_dec, wTdec, 512, 32000);
  k_gather<<<4096, 128, 0, stream>>>(x, emb, eA);

  // m = softplus(e @ w_mass + b_mass) + eps   (grid 256 WGs)
  gemmT<128, 64, 1><<<dim3(32, 8), b256, 0, stream>>>(eA, wTmass, b_mass, m32, m16, 512, 512);

  for (int it = 0; it < 3; ++it){
    // [G|H] = m @ [w_f1_top | w_f1_bot] -> bf16 [4096, 1024]
    gemmT<128, 128, 4><<<dim3(32, 8), b256, 0, stream>>>(m16, wTf1, nullptr, nullptr, GHb, 512, 1024);
    k_ew1<<<4096, 128, 0, stream>>>(GHb, b_f1, act);
    // F = softplus(act @ w_f2 + b_f2) -> f32 [4096, 512]
    gemmT<128, 64, 2><<<dim3(32, 8), b256, 0, stream>>>(act, wTf2, b_f2, Fbuf, nullptr, 512, 512);
    k_update<<<4096, 128, 0, stream>>>(Fbuf, cfl, m32, m16);
  }

  // logits = m @ w_dec + b_dec -> f32 [4096, 32000]
  gemm256<<<dim3(16 * 125), dim3(512), 131072, stream>>>(m16, wTdec, b_dec, out, 512, 32000, 16);
}

// Round 3
// 444.665 us; speedup vs baseline: 1.4697x; 1.0271x over previous
//
#include <hip/hip_runtime.h>
#include <hip/hip_bf16.h>

#define DEV static __device__ __forceinline__

typedef __attribute__((ext_vector_type(4))) float f32x4;
typedef __attribute__((ext_vector_type(8))) short bf16x8;

DEV unsigned short f2bf(float x){
  __hip_bfloat16 h = __float2bfloat16(x);
  return __builtin_bit_cast(unsigned short, h);
}
DEV float b2f(unsigned short u){
  __hip_bfloat16 h = __builtin_bit_cast(__hip_bfloat16, u);
  return __bfloat162float(h);
}
DEV float softplus_f(float x){ return fmaxf(x, 0.f) + log1pf(expf(-fabsf(x))); }

DEV void gload16(const void* g, void* l){
  __builtin_amdgcn_global_load_lds((const __attribute__((address_space(1))) void*)g,
                                   (__attribute__((address_space(3))) void*)l, 16, 0, 0);
}

template<int N> DEV void waitcnt_vm(){
  if constexpr (N == 0) asm volatile("s_waitcnt vmcnt(0)" ::: "memory");
  else if constexpr (N == 6) asm volatile("s_waitcnt vmcnt(6)" ::: "memory");
  else if constexpr (N == 8) asm volatile("s_waitcnt vmcnt(8)" ::: "memory");
}

// ---------------------------------------------------------------------------
// Transpose + fp32->bf16: in[K][N] f32 -> out[N][K] bf16.
__global__ void k_transpose(const float* __restrict__ in, unsigned short* __restrict__ out,
                            int K, int N){
  __shared__ float t[32][33];
  const int nt = blockIdx.x * 32, kt = blockIdx.y * 32;
  const int r  = threadIdx.x >> 3;
  const int c4 = (threadIdx.x & 7) * 4;
  const float4 v = *(const float4*)(in + (size_t)(kt + r) * N + nt + c4);
  t[r][c4+0] = v.x; t[r][c4+1] = v.y; t[r][c4+2] = v.z; t[r][c4+3] = v.w;
  __syncthreads();
  ushort4 o;
  o.x = f2bf(t[c4+0][r]); o.y = f2bf(t[c4+1][r]);
  o.z = f2bf(t[c4+2][r]); o.w = f2bf(t[c4+3][r]);
  *(ushort4*)(out + (size_t)(nt + r) * K + kt + c4) = o;
}

// Fused 512x512 transposes: z=0 w_mass, z=1 w_f1[:512], z=2 w_f1[512:], z=3 w_f2.
__global__ void k_transpose4(const float* __restrict__ w_mass, const float* __restrict__ w_f1,
                             const float* __restrict__ w_f2, unsigned short* __restrict__ wTmass,
                             unsigned short* __restrict__ wTf1, unsigned short* __restrict__ wTf2){
  __shared__ float t[32][33];
  const float* in; unsigned short* out;
  switch (blockIdx.z){
    case 0:  in = w_mass;            out = wTmass;            break;
    case 1:  in = w_f1;              out = wTf1;              break;
    case 2:  in = w_f1 + 512 * 512;  out = wTf1 + 512 * 512;  break;
    default: in = w_f2;              out = wTf2;              break;
  }
  const int nt = blockIdx.x * 32, kt = blockIdx.y * 32;
  const int r  = threadIdx.x >> 3;
  const int c4 = (threadIdx.x & 7) * 4;
  const float4 v = *(const float4*)(in + (size_t)(kt + r) * 512 + nt + c4);
  t[r][c4+0] = v.x; t[r][c4+1] = v.y; t[r][c4+2] = v.z; t[r][c4+3] = v.w;
  __syncthreads();
  ushort4 o;
  o.x = f2bf(t[c4+0][r]); o.y = f2bf(t[c4+1][r]);
  o.z = f2bf(t[c4+2][r]); o.w = f2bf(t[c4+3][r]);
  *(ushort4*)(out + (size_t)(nt + r) * 512 + kt + c4) = o;
}

// Gather emb[x] -> bf16 [4096][512].
__global__ void k_gather(const int* __restrict__ x, const float* __restrict__ emb,
                         unsigned short* __restrict__ eA){
  const int t = blockIdx.x;
  const int idx = x[t];
  const float4 v = ((const float4*)(emb + (size_t)idx * 512))[threadIdx.x];
  ushort4 o; o.x = f2bf(v.x); o.y = f2bf(v.y); o.z = f2bf(v.z); o.w = f2bf(v.w);
  ((ushort4*)(eA + (size_t)t * 512))[threadIdx.x] = o;
}

// act[b,s,:] = bf16(tanh(G[b,s]+H[b,s+1]+b_f1)), act[b,2047,:]=0.  GH is bf16 [4096][1024].
__global__ void k_ew1(const unsigned short* __restrict__ GH, const float* __restrict__ b1,
                      unsigned short* __restrict__ act){
  const int blk = blockIdx.x;
  const int s = blk & 2047;
  const int d = threadIdx.x * 4;
  ushort4 o;
  if (s == 2047){ o.x = o.y = o.z = o.w = 0; }
  else {
    const ushort4 g  = *(const ushort4*)(GH + (size_t)blk * 1024 + d);
    const ushort4 h  = *(const ushort4*)(GH + (size_t)(blk + 1) * 1024 + 512 + d);
    const float4 bb = *(const float4*)(b1 + d);
    o.x = f2bf(tanhf(b2f(g.x) + b2f(h.x) + bb.x));
    o.y = f2bf(tanhf(b2f(g.y) + b2f(h.y) + bb.y));
    o.z = f2bf(tanhf(b2f(g.z) + b2f(h.z) + bb.z));
    o.w = f2bf(tanhf(b2f(g.w) + b2f(h.w) + bb.w));
  }
  *(ushort4*)(act + (size_t)blk * 512 + d) = o;
}

// m = max(m + dt*(F[s-1]-F[s]), eps), zero-flux boundaries.
__global__ void k_update(const float* __restrict__ F, const float* __restrict__ cfl,
                         float* __restrict__ m32, unsigned short* __restrict__ m16){
  const int blk = blockIdx.x;
  const int s = blk & 2047;
  const int d = threadIdx.x * 4;
  const float dt = 1.f / (1.f + expf(-cfl[0]));
  float4 fp = make_float4(0.f,0.f,0.f,0.f), fc = make_float4(0.f,0.f,0.f,0.f);
  if (s > 0)    fp = *(const float4*)(F + (size_t)(blk - 1) * 512 + d);
  if (s < 2047) fc = *(const float4*)(F + (size_t)blk * 512 + d);
  float4 mv = *(const float4*)(m32 + (size_t)blk * 512 + d);
  mv.x = fmaxf(mv.x + dt * (fp.x - fc.x), 1e-6f);
  mv.y = fmaxf(mv.y + dt * (fp.y - fc.y), 1e-6f);
  mv.z = fmaxf(mv.z + dt * (fp.z - fc.z), 1e-6f);
  mv.w = fmaxf(mv.w + dt * (fp.w - fc.w), 1e-6f);
  *(float4*)(m32 + (size_t)blk * 512 + d) = mv;
  ushort4 o; o.x = f2bf(mv.x); o.y = f2bf(mv.y); o.z = f2bf(mv.z); o.w = f2bf(mv.w);
  *(ushort4*)(m16 + (size_t)blk * 512 + d) = o;
}

// ---------------------------------------------------------------------------
// Unified pipelined GEMM: C[M,N] = A[M,K] @ Bt[N,K]^T, bf16 in, f32 acc.
// BMxBN tile, BK=64, WMxWN wave grid, NT k-tiles (K = NT*64), dbuf LDS,
// counted-vmcnt prefetch depth 2 (never drains to 0 mid-loop).
// EPI: 1 softplus(x+bias)+eps -> f32 outF + bf16 outBf
//      2 softplus(x+bias) -> f32 outF
//      3 x+bias -> f32 outF
//      4 raw x -> bf16 outBf
// Grid: 1-D, nwg % 8 == 0, nbx row-tiles; XCD-chunked bijective swizzle.
template<int BM, int BN, int WM, int WN, int NT, int EPI>
__global__ __launch_bounds__(WM * WN * 64, 2)
void gemmP(const unsigned short* __restrict__ A, const unsigned short* __restrict__ Bt,
           const float* __restrict__ bias, float* __restrict__ outF,
           unsigned short* __restrict__ outBf, int N, int nbx)
{
  constexpr int NW = WM * WN;
  constexpr int FA = BM / (WM * 16);     // A frags per wave
  constexpr int FB = BN / (WN * 16);     // B frags per wave
  constexpr int GA = BM / (8 * NW);      // A gloads per wave per tile
  constexpr int GB = BN / (8 * NW);      // B gloads per wave per tile
  constexpr int VC = GA + GB;            // counted vmcnt
  constexpr int LA = BM * 64;            // shorts per A buffer
  constexpr int LB = BN * 64;
  constexpr int K  = NT * 64;

  extern __shared__ unsigned short lds[];   // [2][LA | LB]
  const int tid  = threadIdx.x;
  const int lane = tid & 63;
  const int w    = tid >> 6;
  const int wr   = w / WN;
  const int wc   = w % WN;

  const int nwg = gridDim.x;
  const int cpx = nwg >> 3;
  const int swz = ((int)blockIdx.x & 7) * cpx + ((int)blockIdx.x >> 3);
  const int rowA0 = (swz % nbx) * BM;
  const int rowB0 = (swz / nbx) * BN;

  const int subr = lane >> 3;
  const int cc   = lane & 7;

  auto stage = [&](int kt, int buf){
    unsigned short* la = lds + buf * (LA + LB);
    unsigned short* lb = la + LA;
    const int k0 = kt * 64;
    #pragma unroll
    for (int i = 0; i < GA; i++){
      const int sub = w * GA + i;
      const int r   = sub * 8 + subr;
      const int cs  = cc ^ (r & 7);
      gload16(A + (size_t)(rowA0 + r) * K + k0 + cs * 8, la + sub * 512);
    }
    #pragma unroll
    for (int i = 0; i < GB; i++){
      const int sub = w * GB + i;
      const int r   = sub * 8 + subr;
      const int cs  = cc ^ (r & 7);
      gload16(Bt + (size_t)(rowB0 + r) * K + k0 + cs * 8, lb + sub * 512);
    }
  };

  f32x4 acc[FA][FB];
  const f32x4 z = {0.f, 0.f, 0.f, 0.f};
  #pragma unroll
  for (int i = 0; i < FA; i++)
    #pragma unroll
    for (int j = 0; j < FB; j++) acc[i][j] = z;

  // prologue: stage tiles 0 and 1; wait for tile 0 (tile 1's VC loads may remain).
  stage(0, 0);
  stage(1, 1);
  waitcnt_vm<VC>();
  __builtin_amdgcn_s_barrier();
  __builtin_amdgcn_sched_barrier(0);

  #pragma unroll
  for (int t = 0; t < NT; ++t){
    const int cur = t & 1;
    const unsigned short* la = lds + cur * (LA + LB);
    const unsigned short* lb = la + LA;

    #pragma unroll
    for (int ks = 0; ks < 2; ks++){
      bf16x8 af[FA], bfr[FB];
      #pragma unroll
      for (int i = 0; i < FA; i++){
        const int ra = wr * (BM / WM) + i * 16 + (lane & 15);
        const int ka = (ks * 4 + (lane >> 4)) ^ (ra & 7);
        af[i] = *(const bf16x8*)(la + ra * 64 + ka * 8);
      }
      #pragma unroll
      for (int j = 0; j < FB; j++){
        const int rb = wc * (BN / WN) + j * 16 + (lane & 15);
        const int kb = (ks * 4 + (lane >> 4)) ^ (rb & 7);
        bfr[j] = *(const bf16x8*)(lb + rb * 64 + kb * 8);
      }
      if (ks == 1){
        // this wave's reads of buf[cur] retired; block barrier; then overwrite
        // buf[cur] with tile t+2 while MFMAs below chew on registers.
        asm volatile("s_waitcnt lgkmcnt(0)" ::: "memory");
        __builtin_amdgcn_sched_barrier(0);
        __builtin_amdgcn_s_barrier();
        __builtin_amdgcn_sched_barrier(0);
        if (t + 2 < NT) stage(t + 2, cur);
      }
      __builtin_amdgcn_s_setprio(1);
      #pragma unroll
      for (int i = 0; i < FA; i++)
        #pragma unroll
        for (int j = 0; j < FB; j++)
          acc[i][j] = __builtin_amdgcn_mfma_f32_16x16x32_bf16(af[i], bfr[j], acc[i][j], 0, 0, 0);
      __builtin_amdgcn_s_setprio(0);
    }

    if (t < NT - 1){
      // tile t+1 landed for this wave once only t+2's VC loads remain in flight;
      // the barrier extends the guarantee block-wide.
      if (t + 2 < NT) waitcnt_vm<VC>();
      else            waitcnt_vm<0>();
      __builtin_amdgcn_s_barrier();
      __builtin_amdgcn_sched_barrier(0);
    }
  }

  // epilogue: D row = (lane>>4)*4 + reg, col = lane&15 per 16x16 fragment.
  const int r4 = (lane >> 4) * 4;
  const int cl = lane & 15;
  #pragma unroll
  for (int j = 0; j < FB; j++){
    const int col = rowB0 + wc * (BN / WN) + j * 16 + cl;
    const float bv = (EPI != 4) ? bias[col] : 0.f;
    #pragma unroll
    for (int i = 0; i < FA; i++){
      const int row0 = rowA0 + wr * (BM / WM) + i * 16 + r4;
      #pragma unroll
      for (int r = 0; r < 4; r++){
        float v = acc[i][j][r];
        if (EPI == 1)      v = softplus_f(v + bv) + 1e-6f;
        else if (EPI == 2) v = softplus_f(v + bv);
        else if (EPI == 3) v = v + bv;
        const size_t o = (size_t)(row0 + r) * N + col;
        if (EPI == 4){
          outBf[o] = f2bf(v);
        } else {
          outF[o] = v;
          if (EPI == 1) outBf[o] = f2bf(v);
        }
      }
    }
  }
}

// ---------------------------------------------------------------------------
extern "C" void kernel_launch(void* const* d_in, const int* in_sizes, int n_in,
                              void* d_out, int out_size, void* d_ws, size_t ws_size,
                              hipStream_t stream) {
  const int*   x      = (const int*)  d_in[0];
  const float* emb    = (const float*)d_in[1];
  const float* w_mass = (const float*)d_in[2];
  const float* b_mass = (const float*)d_in[3];
  const float* w_f1   = (const float*)d_in[4];
  const float* b_f1   = (const float*)d_in[5];
  const float* w_f2   = (const float*)d_in[6];
  const float* b_f2   = (const float*)d_in[7];
  const float* cfl    = (const float*)d_in[8];
  const float* w_dec  = (const float*)d_in[9];
  const float* b_dec  = (const float*)d_in[10];
  float* out = (float*)d_out;

  char* ws = (char*)d_ws;
  size_t off = 0;
  auto alloc = [&](size_t bytes) -> void* {
    void* p = ws + off;
    off += (bytes + 255) & ~(size_t)255;
    return p;
  };
  unsigned short* wTdec  = (unsigned short*)alloc((size_t)32000 * 512 * 2);
  unsigned short* eA     = (unsigned short*)alloc((size_t)4096 * 512 * 2);
  unsigned short* wTmass = (unsigned short*)alloc((size_t)512 * 512 * 2);
  unsigned short* wTf1   = (unsigned short*)alloc((size_t)1024 * 512 * 2);
  unsigned short* wTf2   = (unsigned short*)alloc((size_t)512 * 512 * 2);
  float*          m32    = (float*)         alloc((size_t)4096 * 512 * 4);
  unsigned short* m16    = (unsigned short*)alloc((size_t)4096 * 512 * 2);
  unsigned short* GHb    = (unsigned short*)alloc((size_t)4096 * 1024 * 2);
  unsigned short* act    = (unsigned short*)alloc((size_t)4096 * 512 * 2);
  float*          Fbuf   = (float*)         alloc((size_t)4096 * 512 * 4);

  // dynamic-LDS caps (>= 64 KiB instantiations)
  hipFuncSetAttribute(reinterpret_cast<const void*>(&gemmP<128,128,2,2,8,4>),
                      hipFuncAttributeMaxDynamicSharedMemorySize, 65536);
  hipFuncSetAttribute(reinterpret_cast<const void*>(&gemmP<256,256,2,4,8,3>),
                      hipFuncAttributeMaxDynamicSharedMemorySize, 131072);

  const dim3 b256(256);
  k_transpose4<<<dim3(16, 16, 4), b256, 0, stream>>>(w_mass, w_f1, w_f2, wTmass, wTf1, wTf2);
  k_transpose<<<dim3(1000, 16), b256, 0, stream>>>(w_dec, wTdec, 512, 32000);
  k_gather<<<4096, 128, 0, stream>>>(x, emb, eA);

  // m = softplus(e @ w_mass + b_mass) + eps   (256 WGs, LDS 48 KiB)
  gemmP<128, 64, 2, 2, 8, 1><<<256, b256, 49152, stream>>>(eA, wTmass, b_mass, m32, m16, 512, 32);

  for (int it = 0; it < 3; ++it){
    // [G|H] = m @ [w_f1_top | w_f1_bot] -> bf16 [4096, 1024]   (LDS 64 KiB)
    gemmP<128, 128, 2, 2, 8, 4><<<256, b256, 65536, stream>>>(m16, wTf1, nullptr, nullptr, GHb, 1024, 32);
    k_ew1<<<4096, 128, 0, stream>>>(GHb, b_f1, act);
    // F = softplus(act @ w_f2 + b_f2) -> f32 [4096, 512]
    gemmP<128, 64, 2, 2, 8, 2><<<256, b256, 49152, stream>>>(act, wTf2, b_f2, Fbuf, nullptr, 512, 32);
    k_update<<<4096, 128, 0, stream>>>(Fbuf, cfl, m32, m16);
  }

  // logits = m @ w_dec + b_dec -> f32 [4096, 32000]   (2000 WGs, LDS 128 KiB)
  gemmP<256, 256, 2, 4, 8, 3><<<2000, dim3(512), 131072, stream>>>(m16, wTdec, b_dec, out, nullptr, 32000, 16);
}

// Round 4
// 429.519 us; speedup vs baseline: 1.5216x; 1.0353x over previous
//
#include <hip/hip_runtime.h>
#include <hip/hip_bf16.h>

#define DEV static __device__ __forceinline__

typedef __attribute__((ext_vector_type(4))) float f32x4;
typedef __attribute__((ext_vector_type(8))) short bf16x8;

DEV unsigned short f2bf(float x){
  __hip_bfloat16 h = __float2bfloat16(x);
  return __builtin_bit_cast(unsigned short, h);
}
DEV float softplus_f(float x){ return fmaxf(x, 0.f) + log1pf(expf(-fabsf(x))); }

DEV void gload16(const void* g, void* l){
  __builtin_amdgcn_global_load_lds((const __attribute__((address_space(1))) void*)g,
                                   (__attribute__((address_space(3))) void*)l, 16, 0, 0);
}

template<int N> DEV void waitcnt_vm(){
  if constexpr (N == 0) asm volatile("s_waitcnt vmcnt(0)" ::: "memory");
  else if constexpr (N == 5) asm volatile("s_waitcnt vmcnt(5)" ::: "memory");
  else if constexpr (N == 6) asm volatile("s_waitcnt vmcnt(6)" ::: "memory");
  else if constexpr (N == 7) asm volatile("s_waitcnt vmcnt(7)" ::: "memory");
  else if constexpr (N == 8) asm volatile("s_waitcnt vmcnt(8)" ::: "memory");
}

// ---------------------------------------------------------------------------
// Transpose + fp32->bf16: in[K][N] f32 -> out[N][K] bf16.
__global__ void k_transpose(const float* __restrict__ in, unsigned short* __restrict__ out,
                            int K, int N){
  __shared__ float t[32][33];
  const int nt = blockIdx.x * 32, kt = blockIdx.y * 32;
  const int r  = threadIdx.x >> 3;
  const int c4 = (threadIdx.x & 7) * 4;
  const float4 v = *(const float4*)(in + (size_t)(kt + r) * N + nt + c4);
  t[r][c4+0] = v.x; t[r][c4+1] = v.y; t[r][c4+2] = v.z; t[r][c4+3] = v.w;
  __syncthreads();
  ushort4 o;
  o.x = f2bf(t[c4+0][r]); o.y = f2bf(t[c4+1][r]);
  o.z = f2bf(t[c4+2][r]); o.w = f2bf(t[c4+3][r]);
  *(ushort4*)(out + (size_t)(nt + r) * K + kt + c4) = o;
}

// Fused 512x512 transposes: z=0 w_mass, z=1 w_f1[:512], z=2 w_f1[512:], z=3 w_f2.
__global__ void k_transpose4(const float* __restrict__ w_mass, const float* __restrict__ w_f1,
                             const float* __restrict__ w_f2, unsigned short* __restrict__ wTmass,
                             unsigned short* __restrict__ wTf1, unsigned short* __restrict__ wTf2){
  __shared__ float t[32][33];
  const float* in; unsigned short* out;
  switch (blockIdx.z){
    case 0:  in = w_mass;            out = wTmass;            break;
    case 1:  in = w_f1;              out = wTf1;              break;
    case 2:  in = w_f1 + 512 * 512;  out = wTf1 + 512 * 512;  break;
    default: in = w_f2;              out = wTf2;              break;
  }
  const int nt = blockIdx.x * 32, kt = blockIdx.y * 32;
  const int r  = threadIdx.x >> 3;
  const int c4 = (threadIdx.x & 7) * 4;
  const float4 v = *(const float4*)(in + (size_t)(kt + r) * 512 + nt + c4);
  t[r][c4+0] = v.x; t[r][c4+1] = v.y; t[r][c4+2] = v.z; t[r][c4+3] = v.w;
  __syncthreads();
  ushort4 o;
  o.x = f2bf(t[c4+0][r]); o.y = f2bf(t[c4+1][r]);
  o.z = f2bf(t[c4+2][r]); o.w = f2bf(t[c4+3][r]);
  *(ushort4*)(out + (size_t)(nt + r) * 512 + kt + c4) = o;
}

// Gather emb[x] -> bf16 [4096][512]; block 4096 zeroes the two pad rows.
__global__ void k_gather(const int* __restrict__ x, const float* __restrict__ emb,
                         unsigned short* __restrict__ eA,
                         unsigned short* __restrict__ m16_pad,    // m16 row 4096
                         unsigned short* __restrict__ act_pad0){  // act_pad row 0
  const int t = blockIdx.x;
  if (t == 4096){
    const ushort4 z = {0, 0, 0, 0};
    ((ushort4*)m16_pad)[threadIdx.x] = z;
    ((ushort4*)act_pad0)[threadIdx.x] = z;
    return;
  }
  const int idx = x[t];
  const float4 v = ((const float4*)(emb + (size_t)idx * 512))[threadIdx.x];
  ushort4 o; o.x = f2bf(v.x); o.y = f2bf(v.y); o.z = f2bf(v.z); o.w = f2bf(v.w);
  ((ushort4*)(eA + (size_t)t * 512))[threadIdx.x] = o;
}

// ---------------------------------------------------------------------------
// Unified pipelined GEMM (mass + decoder): C[M,N] = A[M,K] @ Bt[N,K]^T.
// EPI: 1 softplus(x+bias)+eps -> f32 outF + bf16 outBf;  3 x+bias -> f32 outF.
template<int BM, int BN, int WM, int WN, int NT, int EPI>
__global__ __launch_bounds__(WM * WN * 64, 2)
void gemmP(const unsigned short* __restrict__ A, const unsigned short* __restrict__ Bt,
           const float* __restrict__ bias, float* __restrict__ outF,
           unsigned short* __restrict__ outBf, int N, int nbx)
{
  constexpr int NW = WM * WN;
  constexpr int FA = BM / (WM * 16);
  constexpr int FB = BN / (WN * 16);
  constexpr int GA = BM / (8 * NW);
  constexpr int GB = BN / (8 * NW);
  constexpr int VC = GA + GB;
  constexpr int LA = BM * 64;
  constexpr int LB = BN * 64;
  constexpr int K  = NT * 64;

  extern __shared__ unsigned short lds[];
  const int tid  = threadIdx.x;
  const int lane = tid & 63;
  const int w    = tid >> 6;
  const int wr   = w / WN;
  const int wc   = w % WN;

  const int nwg = gridDim.x;
  const int cpx = nwg >> 3;
  const int swz = ((int)blockIdx.x & 7) * cpx + ((int)blockIdx.x >> 3);
  const int rowA0 = (swz % nbx) * BM;
  const int rowB0 = (swz / nbx) * BN;

  const int subr = lane >> 3;
  const int cc   = lane & 7;

  auto stage = [&](int kt, int buf){
    unsigned short* la = lds + buf * (LA + LB);
    unsigned short* lb = la + LA;
    const int k0 = kt * 64;
    #pragma unroll
    for (int i = 0; i < GA; i++){
      const int sub = w * GA + i;
      const int r   = sub * 8 + subr;
      const int cs  = cc ^ (r & 7);
      gload16(A + (size_t)(rowA0 + r) * K + k0 + cs * 8, la + sub * 512);
    }
    #pragma unroll
    for (int i = 0; i < GB; i++){
      const int sub = w * GB + i;
      const int r   = sub * 8 + subr;
      const int cs  = cc ^ (r & 7);
      gload16(Bt + (size_t)(rowB0 + r) * K + k0 + cs * 8, lb + sub * 512);
    }
  };

  f32x4 acc[FA][FB];
  const f32x4 z = {0.f, 0.f, 0.f, 0.f};
  #pragma unroll
  for (int i = 0; i < FA; i++)
    #pragma unroll
    for (int j = 0; j < FB; j++) acc[i][j] = z;

  stage(0, 0);
  stage(1, 1);
  waitcnt_vm<VC>();
  __builtin_amdgcn_s_barrier();
  __builtin_amdgcn_sched_barrier(0);

  #pragma unroll
  for (int t = 0; t < NT; ++t){
    const int cur = t & 1;
    const unsigned short* la = lds + cur * (LA + LB);
    const unsigned short* lb = la + LA;

    #pragma unroll
    for (int ks = 0; ks < 2; ks++){
      bf16x8 af[FA], bfr[FB];
      #pragma unroll
      for (int i = 0; i < FA; i++){
        const int ra = wr * (BM / WM) + i * 16 + (lane & 15);
        const int ka = (ks * 4 + (lane >> 4)) ^ (ra & 7);
        af[i] = *(const bf16x8*)(la + ra * 64 + ka * 8);
      }
      #pragma unroll
      for (int j = 0; j < FB; j++){
        const int rb = wc * (BN / WN) + j * 16 + (lane & 15);
        const int kb = (ks * 4 + (lane >> 4)) ^ (rb & 7);
        bfr[j] = *(const bf16x8*)(lb + rb * 64 + kb * 8);
      }
      if (ks == 1){
        asm volatile("s_waitcnt lgkmcnt(0)" ::: "memory");
        __builtin_amdgcn_sched_barrier(0);
        __builtin_amdgcn_s_barrier();
        __builtin_amdgcn_sched_barrier(0);
        if (t + 2 < NT) stage(t + 2, cur);
      }
      __builtin_amdgcn_s_setprio(1);
      #pragma unroll
      for (int i = 0; i < FA; i++)
        #pragma unroll
        for (int j = 0; j < FB; j++)
          acc[i][j] = __builtin_amdgcn_mfma_f32_16x16x32_bf16(af[i], bfr[j], acc[i][j], 0, 0, 0);
      __builtin_amdgcn_s_setprio(0);
    }

    if (t < NT - 1){
      if (t + 2 < NT) waitcnt_vm<VC>();
      else            waitcnt_vm<0>();
      __builtin_amdgcn_s_barrier();
      __builtin_amdgcn_sched_barrier(0);
    }
  }

  const int r4 = (lane >> 4) * 4;
  const int cl = lane & 15;
  #pragma unroll
  for (int j = 0; j < FB; j++){
    const int col = rowB0 + wc * (BN / WN) + j * 16 + cl;
    const float bv = bias[col];
    #pragma unroll
    for (int i = 0; i < FA; i++){
      const int row0 = rowA0 + wr * (BM / WM) + i * 16 + r4;
      #pragma unroll
      for (int r = 0; r < 4; r++){
        float v = acc[i][j][r];
        if (EPI == 1) v = softplus_f(v + bv) + 1e-6f;
        else          v = v + bv;
        const size_t o = (size_t)(row0 + r) * N + col;
        outF[o] = v;
        if (EPI == 1) outBf[o] = f2bf(v);
      }
    }
  }
}

// ---------------------------------------------------------------------------
// Fused flux kernels, 64x64 tile, dual accumulators via shifted-A fragments.
// MODE 0: act[s] = tanh(m[s]@W1a[:,ct] + m[s+1]@W1b[:,ct] + b1) -> act_pad[s+1];
//         zero row when (s&2047)==2047.  A = m16 (pad row 4096 = 0).
// MODE 1: F[s] = sp(act[s]@w_f2+b2), F[s-1] = sp(act[s-1]@w_f2+b2);
//         m = max(m + dt*(F[s-1]-F[s]), eps) with boundary masks.
//         A = act_pad (act[s] at row s+1; row 0 = 0).
template<int MODE>
__global__ __launch_bounds__(256, 2)
void fluxK(const unsigned short* __restrict__ A, const unsigned short* __restrict__ Bt,
           const float* __restrict__ bias, const float* __restrict__ cfl,
           float* __restrict__ m32, unsigned short* __restrict__ m16,
           unsigned short* __restrict__ act_pad)
{
  constexpr int ASUB = 9;                     // 72 staged rows (need 65)
  constexpr int BSUB = (MODE == 0) ? 16 : 8;  // MODE0: two 64-col panels (W1a,W1b)
  constexpr int GA = 3;                       // per-wave A gloads (1 dup slot)
  constexpr int GB = (MODE == 0) ? 4 : 2;
  constexpr int VC = GA + GB;
  constexpr int ABUF = ASUB * 512;
  constexpr int BBUF = BSUB * 512;
  constexpr int BUFSZ = ABUF + BBUF;

  extern __shared__ unsigned short lds[];
  const int tid  = threadIdx.x;
  const int lane = tid & 63;
  const int w    = tid >> 6;
  const int wr   = w >> 1, wc = w & 1;
  const int rowA0 = blockIdx.x * 64;
  const int col0  = blockIdx.y * 64;
  const int subr = lane >> 3;
  const int cc   = lane & 7;

  auto stage = [&](int kt, int buf){
    unsigned short* la = lds + buf * BUFSZ;
    unsigned short* lb = la + ABUF;
    const int k0 = kt * 64;
    #pragma unroll
    for (int i = 0; i < GA; i++){
      const int si  = w * GA + i;
      const int sub = si > 8 ? 8 : si;           // dup-write of last subtile is benign
      const int r   = sub * 8 + subr;
      const int cs  = cc ^ subr;                 // r&7 == subr
      gload16(A + (size_t)(rowA0 + r) * 512 + k0 + cs * 8, la + sub * 512);
    }
    #pragma unroll
    for (int i = 0; i < GB; i++){
      const int sub = w * GB + i;
      int grow;
      if (MODE == 0) grow = (sub < 8) ? (col0 + sub * 8 + subr)
                                      : (512 + col0 + (sub - 8) * 8 + subr);
      else           grow = col0 + sub * 8 + subr;
      const int cs = cc ^ subr;
      gload16(Bt + (size_t)grow * 512 + k0 + cs * 8, lb + sub * 512);
    }
  };

  f32x4 acc1[2][2], acc2[2][2];
  const f32x4 z = {0.f, 0.f, 0.f, 0.f};
  #pragma unroll
  for (int i = 0; i < 2; i++)
    #pragma unroll
    for (int j = 0; j < 2; j++){ acc1[i][j] = z; acc2[i][j] = z; }

  stage(0, 0);
  stage(1, 1);
  waitcnt_vm<VC>();
  __builtin_amdgcn_s_barrier();
  __builtin_amdgcn_sched_barrier(0);

  #pragma unroll
  for (int t = 0; t < 8; ++t){
    const int cur = t & 1;
    const unsigned short* la = lds + cur * BUFSZ;
    const unsigned short* lb = la + ABUF;

    #pragma unroll
    for (int ks = 0; ks < 2; ks++){
      bf16x8 a0[2], a1[2], b0[2], b1v[2];
      #pragma unroll
      for (int i = 0; i < 2; i++){
        const int ra  = wr * 32 + i * 16 + (lane & 15);
        const int ka  = (ks * 4 + (lane >> 4)) ^ (ra & 7);
        a0[i] = *(const bf16x8*)(la + ra * 64 + ka * 8);          // rows s (unshifted)
        const int ra1 = ra + 1;
        const int ka1 = (ks * 4 + (lane >> 4)) ^ (ra1 & 7);
        a1[i] = *(const bf16x8*)(la + ra1 * 64 + ka1 * 8);        // rows s+1 (shifted)
      }
      #pragma unroll
      for (int j = 0; j < 2; j++){
        const int rb = wc * 32 + j * 16 + (lane & 15);
        const int kb = (ks * 4 + (lane >> 4)) ^ (rb & 7);
        b0[j] = *(const bf16x8*)(lb + rb * 64 + kb * 8);
        if (MODE == 0) b1v[j] = *(const bf16x8*)(lb + (64 + rb) * 64 + kb * 8);
      }
      if (ks == 1){
        asm volatile("s_waitcnt lgkmcnt(0)" ::: "memory");
        __builtin_amdgcn_sched_barrier(0);
        __builtin_amdgcn_s_barrier();
        __builtin_amdgcn_sched_barrier(0);
        if (t + 2 < 8) stage(t + 2, cur);
      }
      __builtin_amdgcn_s_setprio(1);
      #pragma unroll
      for (int i = 0; i < 2; i++)
        #pragma unroll
        for (int j = 0; j < 2; j++){
          if (MODE == 0){
            acc1[i][j] = __builtin_amdgcn_mfma_f32_16x16x32_bf16(a0[i], b0[j],  acc1[i][j], 0, 0, 0);
            acc2[i][j] = __builtin_amdgcn_mfma_f32_16x16x32_bf16(a1[i], b1v[j], acc2[i][j], 0, 0, 0);
          } else {
            acc1[i][j] = __builtin_amdgcn_mfma_f32_16x16x32_bf16(a1[i], b0[j], acc1[i][j], 0, 0, 0); // F[s]
            acc2[i][j] = __builtin_amdgcn_mfma_f32_16x16x32_bf16(a0[i], b0[j], acc2[i][j], 0, 0, 0); // F[s-1]
          }
        }
      __builtin_amdgcn_s_setprio(0);
    }

    if (t < 7){
      if (t + 2 < 8) waitcnt_vm<VC>();
      else           waitcnt_vm<0>();
      __builtin_amdgcn_s_barrier();
      __builtin_amdgcn_sched_barrier(0);
    }
  }

  const int r4 = (lane >> 4) * 4;
  const int cl = lane & 15;
  if (MODE == 0){
    #pragma unroll
    for (int j = 0; j < 2; j++){
      const int col = col0 + wc * 32 + j * 16 + cl;
      const float bv = bias[col];
      #pragma unroll
      for (int i = 0; i < 2; i++){
        #pragma unroll
        for (int r = 0; r < 4; r++){
          const int s = rowA0 + wr * 32 + i * 16 + r4 + r;
          const float v = tanhf(acc1[i][j][r] + acc2[i][j][r] + bv);
          act_pad[(size_t)(s + 1) * 512 + col] = ((s & 2047) == 2047) ? 0 : f2bf(v);
        }
      }
    }
  } else {
    const float dt = 1.f / (1.f + expf(-cfl[0]));
    #pragma unroll
    for (int j = 0; j < 2; j++){
      const int col = col0 + wc * 32 + j * 16 + cl;
      const float bv = bias[col];
      #pragma unroll
      for (int i = 0; i < 2; i++){
        #pragma unroll
        for (int r = 0; r < 4; r++){
          const int s = rowA0 + wr * 32 + i * 16 + r4 + r;
          const float fc = ((s & 2047) == 2047) ? 0.f : softplus_f(acc1[i][j][r] + bv);
          const float fp = ((s & 2047) == 0)    ? 0.f : softplus_f(acc2[i][j][r] + bv);
          const size_t o = (size_t)s * 512 + col;
          const float mv = fmaxf(m32[o] + dt * (fp - fc), 1e-6f);
          m32[o] = mv;
          m16[o] = f2bf(mv);
        }
      }
    }
  }
}

// ---------------------------------------------------------------------------
extern "C" void kernel_launch(void* const* d_in, const int* in_sizes, int n_in,
                              void* d_out, int out_size, void* d_ws, size_t ws_size,
                              hipStream_t stream) {
  const int*   x      = (const int*)  d_in[0];
  const float* emb    = (const float*)d_in[1];
  const float* w_mass = (const float*)d_in[2];
  const float* b_mass = (const float*)d_in[3];
  const float* w_f1   = (const float*)d_in[4];
  const float* b_f1   = (const float*)d_in[5];
  const float* w_f2   = (const float*)d_in[6];
  const float* b_f2   = (const float*)d_in[7];
  const float* cfl    = (const float*)d_in[8];
  const float* w_dec  = (const float*)d_in[9];
  const float* b_dec  = (const float*)d_in[10];
  float* out = (float*)d_out;

  char* ws = (char*)d_ws;
  size_t off = 0;
  auto alloc = [&](size_t bytes) -> void* {
    void* p = ws + off;
    off += (bytes + 255) & ~(size_t)255;
    return p;
  };
  unsigned short* wTdec   = (unsigned short*)alloc((size_t)32000 * 512 * 2);
  unsigned short* eA      = (unsigned short*)alloc((size_t)4096 * 512 * 2);
  unsigned short* wTmass  = (unsigned short*)alloc((size_t)512 * 512 * 2);
  unsigned short* wTf1    = (unsigned short*)alloc((size_t)1024 * 512 * 2);
  unsigned short* wTf2    = (unsigned short*)alloc((size_t)512 * 512 * 2);
  float*          m32     = (float*)         alloc((size_t)4096 * 512 * 4);
  unsigned short* m16     = (unsigned short*)alloc((size_t)4097 * 512 * 2);  // +1 pad row (zero)
  unsigned short* act_pad = (unsigned short*)alloc((size_t)4104 * 512 * 2);  // row 0 = zero pad

  hipFuncSetAttribute(reinterpret_cast<const void*>(&gemmP<256,256,2,4,8,3>),
                      hipFuncAttributeMaxDynamicSharedMemorySize, 131072);
  hipFuncSetAttribute(reinterpret_cast<const void*>(&fluxK<0>),
                      hipFuncAttributeMaxDynamicSharedMemorySize, 65536);
  hipFuncSetAttribute(reinterpret_cast<const void*>(&fluxK<1>),
                      hipFuncAttributeMaxDynamicSharedMemorySize, 65536);

  const dim3 b256(256);
  k_transpose4<<<dim3(16, 16, 4), b256, 0, stream>>>(w_mass, w_f1, w_f2, wTmass, wTf1, wTf2);
  k_transpose<<<dim3(1000, 16), b256, 0, stream>>>(w_dec, wTdec, 512, 32000);
  k_gather<<<4097, 128, 0, stream>>>(x, emb, eA, m16 + (size_t)4096 * 512, act_pad);

  // m = softplus(e @ w_mass + b_mass) + eps
  gemmP<128, 64, 2, 2, 8, 1><<<256, b256, 49152, stream>>>(eA, wTmass, b_mass, m32, m16, 512, 32);

  constexpr int FLUXA_LDS = (9 * 512 + 16 * 512) * 2 * 2;  // 51200 B
  constexpr int FLUXB_LDS = (9 * 512 +  8 * 512) * 2 * 2;  // 34816 B
  for (int it = 0; it < 3; ++it){
    fluxK<0><<<dim3(64, 8), b256, FLUXA_LDS, stream>>>(m16, wTf1, b_f1, nullptr,
                                                       nullptr, nullptr, act_pad);
    fluxK<1><<<dim3(64, 8), b256, FLUXB_LDS, stream>>>(act_pad, wTf2, b_f2, cfl,
                                                       m32, m16, nullptr);
  }

  // logits = m @ w_dec + b_dec -> f32 [4096, 32000]
  gemmP<256, 256, 2, 4, 8, 3><<<2000, dim3(512), 131072, stream>>>(m16, wTdec, b_dec, out, nullptr, 32000, 16);
}

// Round 5
// 414.636 us; speedup vs baseline: 1.5762x; 1.0359x over previous
//
#include <hip/hip_runtime.h>
#include <hip/hip_bf16.h>

#define DEV static __device__ __forceinline__

typedef __attribute__((ext_vector_type(4))) float f32x4;
typedef __attribute__((ext_vector_type(8))) short bf16x8;

DEV unsigned short f2bf(float x){
  __hip_bfloat16 h = __float2bfloat16(x);
  return __builtin_bit_cast(unsigned short, h);
}
DEV float softplus_f(float x){ return fmaxf(x, 0.f) + log1pf(expf(-fabsf(x))); }

DEV void gload16(const void* g, void* l){
  __builtin_amdgcn_global_load_lds((const __attribute__((address_space(1))) void*)g,
                                   (__attribute__((address_space(3))) void*)l, 16, 0, 0);
}

template<int N> DEV void waitcnt_vm(){
  if constexpr (N == 0) asm volatile("s_waitcnt vmcnt(0)" ::: "memory");
  else if constexpr (N == 5) asm volatile("s_waitcnt vmcnt(5)" ::: "memory");
  else if constexpr (N == 6) asm volatile("s_waitcnt vmcnt(6)" ::: "memory");
  else if constexpr (N == 7) asm volatile("s_waitcnt vmcnt(7)" ::: "memory");
  else if constexpr (N == 8) asm volatile("s_waitcnt vmcnt(8)" ::: "memory");
}

// ---------------------------------------------------------------------------
// Merged prep: [0,1024) four 512x512 transposes; [1024,17024) w_dec transpose;
// [17024,19072) gather (2 rows/block); 19072 pad-row zeroing.  256 thr.
__global__ void k_prep(const float* __restrict__ w_mass, const float* __restrict__ w_f1,
                       const float* __restrict__ w_f2, const float* __restrict__ w_dec,
                       const int* __restrict__ x, const float* __restrict__ emb,
                       unsigned short* __restrict__ wTmass, unsigned short* __restrict__ wTf1,
                       unsigned short* __restrict__ wTf2, unsigned short* __restrict__ wTdec,
                       unsigned short* __restrict__ eA,
                       unsigned short* __restrict__ m16_pad, unsigned short* __restrict__ act_pad0){
  __shared__ float t[32][33];
  const int b = blockIdx.x;
  const int tid = threadIdx.x;
  if (b >= 17024){
    const int local = b - 17024;
    if (local == 2048){
      if (tid < 128){
        const ushort4 z = {0, 0, 0, 0};
        ((ushort4*)m16_pad)[tid] = z;
        ((ushort4*)act_pad0)[tid] = z;
      }
      return;
    }
    const int row = local * 2 + (tid >> 7);
    const int c   = tid & 127;
    const int idx = x[row];
    const float4 v = ((const float4*)(emb + (size_t)idx * 512))[c];
    ushort4 o; o.x = f2bf(v.x); o.y = f2bf(v.y); o.z = f2bf(v.z); o.w = f2bf(v.w);
    ((ushort4*)(eA + (size_t)row * 512))[c] = o;
    return;
  }
  const float* in; unsigned short* out; int K, N, bx, by;
  if (b < 1024){
    const int z = b >> 8, idx = b & 255;
    bx = idx & 15; by = idx >> 4; K = 512; N = 512;
    switch (z){
      case 0:  in = w_mass;            out = wTmass;            break;
      case 1:  in = w_f1;              out = wTf1;              break;
      case 2:  in = w_f1 + 512 * 512;  out = wTf1 + 512 * 512;  break;
      default: in = w_f2;              out = wTf2;              break;
    }
  } else {
    const int local = b - 1024;
    bx = local % 1000; by = local / 1000; K = 512; N = 32000;
    in = w_dec; out = wTdec;
  }
  const int nt = bx * 32, kt = by * 32;
  const int r  = tid >> 3;
  const int c4 = (tid & 7) * 4;
  const float4 v = *(const float4*)(in + (size_t)(kt + r) * N + nt + c4);
  t[r][c4+0] = v.x; t[r][c4+1] = v.y; t[r][c4+2] = v.z; t[r][c4+3] = v.w;
  __syncthreads();
  ushort4 o;
  o.x = f2bf(t[c4+0][r]); o.y = f2bf(t[c4+1][r]);
  o.z = f2bf(t[c4+2][r]); o.w = f2bf(t[c4+3][r]);
  *(ushort4*)(out + (size_t)(nt + r) * K + kt + c4) = o;
}

// ---------------------------------------------------------------------------
// Pipelined GEMM (mass): C[M,N] = A[M,K] @ Bt[N,K]^T.
// EPI 1: softplus(x+bias)+eps -> f32 outF + bf16 outBf.
template<int BM, int BN, int WM, int WN, int NT, int EPI>
__global__ __launch_bounds__(WM * WN * 64, 2)
void gemmP(const unsigned short* __restrict__ A, const unsigned short* __restrict__ Bt,
           const float* __restrict__ bias, float* __restrict__ outF,
           unsigned short* __restrict__ outBf, int N, int nbx)
{
  constexpr int NW = WM * WN;
  constexpr int FA = BM / (WM * 16);
  constexpr int FB = BN / (WN * 16);
  constexpr int GA = BM / (8 * NW);
  constexpr int GB = BN / (8 * NW);
  constexpr int VC = GA + GB;
  constexpr int LA = BM * 64;
  constexpr int LB = BN * 64;
  constexpr int K  = NT * 64;

  extern __shared__ unsigned short lds[];
  const int tid  = threadIdx.x;
  const int lane = tid & 63;
  const int w    = tid >> 6;
  const int wr   = w / WN;
  const int wc   = w % WN;

  const int nwg = gridDim.x;
  const int cpx = nwg >> 3;
  const int swz = ((int)blockIdx.x & 7) * cpx + ((int)blockIdx.x >> 3);
  const int rowA0 = (swz % nbx) * BM;
  const int rowB0 = (swz / nbx) * BN;

  const int subr = lane >> 3;
  const int cc   = lane & 7;

  auto stage = [&](int kt, int buf){
    unsigned short* la = lds + buf * (LA + LB);
    unsigned short* lb = la + LA;
    const int k0 = kt * 64;
    #pragma unroll
    for (int i = 0; i < GA; i++){
      const int sub = w * GA + i;
      const int r   = sub * 8 + subr;
      const int cs  = cc ^ (r & 7);
      gload16(A + (size_t)(rowA0 + r) * K + k0 + cs * 8, la + sub * 512);
    }
    #pragma unroll
    for (int i = 0; i < GB; i++){
      const int sub = w * GB + i;
      const int r   = sub * 8 + subr;
      const int cs  = cc ^ (r & 7);
      gload16(Bt + (size_t)(rowB0 + r) * K + k0 + cs * 8, lb + sub * 512);
    }
  };

  f32x4 acc[FA][FB];
  const f32x4 z = {0.f, 0.f, 0.f, 0.f};
  #pragma unroll
  for (int i = 0; i < FA; i++)
    #pragma unroll
    for (int j = 0; j < FB; j++) acc[i][j] = z;

  stage(0, 0);
  stage(1, 1);
  waitcnt_vm<VC>();
  __builtin_amdgcn_s_barrier();
  __builtin_amdgcn_sched_barrier(0);

  #pragma unroll
  for (int t = 0; t < NT; ++t){
    const int cur = t & 1;
    const unsigned short* la = lds + cur * (LA + LB);
    const unsigned short* lb = la + LA;

    #pragma unroll
    for (int ks = 0; ks < 2; ks++){
      bf16x8 af[FA], bfr[FB];
      #pragma unroll
      for (int i = 0; i < FA; i++){
        const int ra = wr * (BM / WM) + i * 16 + (lane & 15);
        const int ka = (ks * 4 + (lane >> 4)) ^ (ra & 7);
        af[i] = *(const bf16x8*)(la + ra * 64 + ka * 8);
      }
      #pragma unroll
      for (int j = 0; j < FB; j++){
        const int rb = wc * (BN / WN) + j * 16 + (lane & 15);
        const int kb = (ks * 4 + (lane >> 4)) ^ (rb & 7);
        bfr[j] = *(const bf16x8*)(lb + rb * 64 + kb * 8);
      }
      if (ks == 1){
        asm volatile("s_waitcnt lgkmcnt(0)" ::: "memory");
        __builtin_amdgcn_sched_barrier(0);
        __builtin_amdgcn_s_barrier();
        __builtin_amdgcn_sched_barrier(0);
        if (t + 2 < NT) stage(t + 2, cur);
      }
      __builtin_amdgcn_s_setprio(1);
      #pragma unroll
      for (int i = 0; i < FA; i++)
        #pragma unroll
        for (int j = 0; j < FB; j++)
          acc[i][j] = __builtin_amdgcn_mfma_f32_16x16x32_bf16(af[i], bfr[j], acc[i][j], 0, 0, 0);
      __builtin_amdgcn_s_setprio(0);
    }

    if (t < NT - 1){
      if (t + 2 < NT) waitcnt_vm<VC>();
      else            waitcnt_vm<0>();
      __builtin_amdgcn_s_barrier();
      __builtin_amdgcn_sched_barrier(0);
    }
  }

  const int r4 = (lane >> 4) * 4;
  const int cl = lane & 15;
  #pragma unroll
  for (int j = 0; j < FB; j++){
    const int col = rowB0 + wc * (BN / WN) + j * 16 + cl;
    const float bv = bias[col];
    #pragma unroll
    for (int i = 0; i < FA; i++){
      const int row0 = rowA0 + wr * (BM / WM) + i * 16 + r4;
      #pragma unroll
      for (int r = 0; r < 4; r++){
        float v = acc[i][j][r];
        if (EPI == 1) v = softplus_f(v + bv) + 1e-6f;
        else          v = v + bv;
        const size_t o = (size_t)(row0 + r) * N + col;
        outF[o] = v;
        if (EPI == 1) outBf[o] = f2bf(v);
      }
    }
  }
}

// ---------------------------------------------------------------------------
// Decoder GEMM: 3-LDS-buffer, one-barrier-per-K-tile pipeline.
// Tile 256x128, BK=64, 8 waves (4M x 2N), 144 KiB dynamic LDS, depth-2 tile prefetch.
// Race ledger: stage(t+2 -> buf[(t+2)%3]) issued right after the iter-t barrier;
// that buffer was last read in iter t-1 and the barrier proves all waves finished.
// vmcnt(6) at iter end (t+2's 6 loads newest) guarantees tile t+1 landed.
__global__ __launch_bounds__(512, 2)
void gemmDec(const unsigned short* __restrict__ A, const unsigned short* __restrict__ Bt,
             const float* __restrict__ bias, float* __restrict__ out, int N, int nbx)
{
  constexpr int BM = 256, BN = 128, NT = 8;
  constexpr int GA = 4, GB = 2;            // gloads per wave per tile
  constexpr int VC = GA + GB;              // 6
  constexpr int LA = BM * 64;              // shorts
  constexpr int LB = BN * 64;
  constexpr int BUF = LA + LB;             // 24576 shorts = 48 KiB
  constexpr int K = NT * 64;

  extern __shared__ unsigned short lds[];  // 3 * BUF
  const int tid  = threadIdx.x;
  const int lane = tid & 63;
  const int w    = tid >> 6;               // 0..7
  const int wr   = w >> 1;                 // 0..3
  const int wc   = w & 1;                  // 0..1

  const int nwg = gridDim.x;
  const int cpx = nwg >> 3;
  const int swz = ((int)blockIdx.x & 7) * cpx + ((int)blockIdx.x >> 3);
  const int rowA0 = (swz % nbx) * BM;
  const int rowB0 = (swz / nbx) * BN;

  const int subr = lane >> 3;
  const int cc   = lane & 7;

  auto stage = [&](int kt, int buf){
    unsigned short* la = lds + buf * BUF;
    unsigned short* lb = la + LA;
    const int k0 = kt * 64;
    #pragma unroll
    for (int i = 0; i < GA; i++){
      const int sub = w * GA + i;          // 0..31
      const int r   = sub * 8 + subr;      // 0..255
      const int cs  = cc ^ (r & 7);
      gload16(A + (size_t)(rowA0 + r) * K + k0 + cs * 8, la + sub * 512);
    }
    #pragma unroll
    for (int i = 0; i < GB; i++){
      const int sub = w * GB + i;          // 0..15
      const int r   = sub * 8 + subr;      // 0..127
      const int cs  = cc ^ (r & 7);
      gload16(Bt + (size_t)(rowB0 + r) * K + k0 + cs * 8, lb + sub * 512);
    }
  };

  f32x4 acc[4][4];
  const f32x4 z = {0.f, 0.f, 0.f, 0.f};
  #pragma unroll
  for (int i = 0; i < 4; i++)
    #pragma unroll
    for (int j = 0; j < 4; j++) acc[i][j] = z;

  stage(0, 0);
  stage(1, 1);
  waitcnt_vm<VC>();                        // tile 0 landed (tile 1's 6 may remain)
  __builtin_amdgcn_s_barrier();
  __builtin_amdgcn_sched_barrier(0);

  #pragma unroll
  for (int t = 0; t < NT; ++t){
    const int cur = t % 3;
    const unsigned short* la = lds + cur * BUF;
    const unsigned short* lb = la + LA;

    // prefetch tile t+2 into buf[(t+2)%3] == buf[(t-1)%3] (idle since iter-t barrier)
    if (t + 2 < NT) stage(t + 2, (t + 2) % 3);
    __builtin_amdgcn_sched_barrier(0);

    #pragma unroll
    for (int ks = 0; ks < 2; ks++){
      bf16x8 af[4], bfr[4];
      #pragma unroll
      for (int i = 0; i < 4; i++){
        const int ra = wr * 64 + i * 16 + (lane & 15);
        const int ka = (ks * 4 + (lane >> 4)) ^ (ra & 7);
        af[i] = *(const bf16x8*)(la + ra * 64 + ka * 8);
      }
      #pragma unroll
      for (int j = 0; j < 4; j++){
        const int rb = wc * 64 + j * 16 + (lane & 15);
        const int kb = (ks * 4 + (lane >> 4)) ^ (rb & 7);
        bfr[j] = *(const bf16x8*)(lb + rb * 64 + kb * 8);
      }
      __builtin_amdgcn_s_setprio(1);
      #pragma unroll
      for (int i = 0; i < 4; i++)
        #pragma unroll
        for (int j = 0; j < 4; j++)
          acc[i][j] = __builtin_amdgcn_mfma_f32_16x16x32_bf16(af[i], bfr[j], acc[i][j], 0, 0, 0);
      __builtin_amdgcn_s_setprio(0);
    }

    if (t < NT - 1){
      // tile t+1 must be resident before next iter's ds_reads.
      if (t + 2 < NT) waitcnt_vm<VC>();    // newest 6 = tile t+2's loads
      else            waitcnt_vm<0>();     // nothing staged this iter
      __builtin_amdgcn_s_barrier();
      __builtin_amdgcn_sched_barrier(0);
    }
  }

  const int r4 = (lane >> 4) * 4;
  const int cl = lane & 15;
  #pragma unroll
  for (int j = 0; j < 4; j++){
    const int col = rowB0 + wc * 64 + j * 16 + cl;
    const float bv = bias[col];
    #pragma unroll
    for (int i = 0; i < 4; i++){
      const int row0 = rowA0 + wr * 64 + i * 16 + r4;
      #pragma unroll
      for (int r = 0; r < 4; r++)
        out[(size_t)(row0 + r) * N + col] = acc[i][j][r] + bv;
    }
  }
}

// ---------------------------------------------------------------------------
// Fused flux kernels, 64x64 tile, dual accumulators via shifted-A fragments.
template<int MODE>
__global__ __launch_bounds__(256, 2)
void fluxK(const unsigned short* __restrict__ A, const unsigned short* __restrict__ Bt,
           const float* __restrict__ bias, const float* __restrict__ cfl,
           float* __restrict__ m32, unsigned short* __restrict__ m16,
           unsigned short* __restrict__ act_pad)
{
  constexpr int ASUB = 9;
  constexpr int BSUB = (MODE == 0) ? 16 : 8;
  constexpr int GA = 3;
  constexpr int GB = (MODE == 0) ? 4 : 2;
  constexpr int VC = GA + GB;
  constexpr int ABUF = ASUB * 512;
  constexpr int BBUF = BSUB * 512;
  constexpr int BUFSZ = ABUF + BBUF;

  extern __shared__ unsigned short lds[];
  const int tid  = threadIdx.x;
  const int lane = tid & 63;
  const int w    = tid >> 6;
  const int wr   = w >> 1, wc = w & 1;
  const int rowA0 = blockIdx.x * 64;
  const int col0  = blockIdx.y * 64;
  const int subr = lane >> 3;
  const int cc   = lane & 7;

  auto stage = [&](int kt, int buf){
    unsigned short* la = lds + buf * BUFSZ;
    unsigned short* lb = la + ABUF;
    const int k0 = kt * 64;
    #pragma unroll
    for (int i = 0; i < GA; i++){
      const int si  = w * GA + i;
      const int sub = si > 8 ? 8 : si;
      const int r   = sub * 8 + subr;
      const int cs  = cc ^ subr;
      gload16(A + (size_t)(rowA0 + r) * 512 + k0 + cs * 8, la + sub * 512);
    }
    #pragma unroll
    for (int i = 0; i < GB; i++){
      const int sub = w * GB + i;
      int grow;
      if (MODE == 0) grow = (sub < 8) ? (col0 + sub * 8 + subr)
                                      : (512 + col0 + (sub - 8) * 8 + subr);
      else           grow = col0 + sub * 8 + subr;
      const int cs = cc ^ subr;
      gload16(Bt + (size_t)grow * 512 + k0 + cs * 8, lb + sub * 512);
    }
  };

  f32x4 acc1[2][2], acc2[2][2];
  const f32x4 z = {0.f, 0.f, 0.f, 0.f};
  #pragma unroll
  for (int i = 0; i < 2; i++)
    #pragma unroll
    for (int j = 0; j < 2; j++){ acc1[i][j] = z; acc2[i][j] = z; }

  stage(0, 0);
  stage(1, 1);
  waitcnt_vm<VC>();
  __builtin_amdgcn_s_barrier();
  __builtin_amdgcn_sched_barrier(0);

  #pragma unroll
  for (int t = 0; t < 8; ++t){
    const int cur = t & 1;
    const unsigned short* la = lds + cur * BUFSZ;
    const unsigned short* lb = la + ABUF;

    #pragma unroll
    for (int ks = 0; ks < 2; ks++){
      bf16x8 a0[2], a1[2], b0[2], b1v[2];
      #pragma unroll
      for (int i = 0; i < 2; i++){
        const int ra  = wr * 32 + i * 16 + (lane & 15);
        const int ka  = (ks * 4 + (lane >> 4)) ^ (ra & 7);
        a0[i] = *(const bf16x8*)(la + ra * 64 + ka * 8);
        const int ra1 = ra + 1;
        const int ka1 = (ks * 4 + (lane >> 4)) ^ (ra1 & 7);
        a1[i] = *(const bf16x8*)(la + ra1 * 64 + ka1 * 8);
      }
      #pragma unroll
      for (int j = 0; j < 2; j++){
        const int rb = wc * 32 + j * 16 + (lane & 15);
        const int kb = (ks * 4 + (lane >> 4)) ^ (rb & 7);
        b0[j] = *(const bf16x8*)(lb + rb * 64 + kb * 8);
        if (MODE == 0) b1v[j] = *(const bf16x8*)(lb + (64 + rb) * 64 + kb * 8);
      }
      if (ks == 1){
        asm volatile("s_waitcnt lgkmcnt(0)" ::: "memory");
        __builtin_amdgcn_sched_barrier(0);
        __builtin_amdgcn_s_barrier();
        __builtin_amdgcn_sched_barrier(0);
        if (t + 2 < 8) stage(t + 2, cur);
      }
      __builtin_amdgcn_s_setprio(1);
      #pragma unroll
      for (int i = 0; i < 2; i++)
        #pragma unroll
        for (int j = 0; j < 2; j++){
          if (MODE == 0){
            acc1[i][j] = __builtin_amdgcn_mfma_f32_16x16x32_bf16(a0[i], b0[j],  acc1[i][j], 0, 0, 0);
            acc2[i][j] = __builtin_amdgcn_mfma_f32_16x16x32_bf16(a1[i], b1v[j], acc2[i][j], 0, 0, 0);
          } else {
            acc1[i][j] = __builtin_amdgcn_mfma_f32_16x16x32_bf16(a1[i], b0[j], acc1[i][j], 0, 0, 0);
            acc2[i][j] = __builtin_amdgcn_mfma_f32_16x16x32_bf16(a0[i], b0[j], acc2[i][j], 0, 0, 0);
          }
        }
      __builtin_amdgcn_s_setprio(0);
    }

    if (t < 7){
      if (t + 2 < 8) waitcnt_vm<VC>();
      else           waitcnt_vm<0>();
      __builtin_amdgcn_s_barrier();
      __builtin_amdgcn_sched_barrier(0);
    }
  }

  const int r4 = (lane >> 4) * 4;
  const int cl = lane & 15;
  if (MODE == 0){
    #pragma unroll
    for (int j = 0; j < 2; j++){
      const int col = col0 + wc * 32 + j * 16 + cl;
      const float bv = bias[col];
      #pragma unroll
      for (int i = 0; i < 2; i++){
        #pragma unroll
        for (int r = 0; r < 4; r++){
          const int s = rowA0 + wr * 32 + i * 16 + r4 + r;
          const float v = tanhf(acc1[i][j][r] + acc2[i][j][r] + bv);
          act_pad[(size_t)(s + 1) * 512 + col] = ((s & 2047) == 2047) ? 0 : f2bf(v);
        }
      }
    }
  } else {
    const float dt = 1.f / (1.f + expf(-cfl[0]));
    #pragma unroll
    for (int j = 0; j < 2; j++){
      const int col = col0 + wc * 32 + j * 16 + cl;
      const float bv = bias[col];
      #pragma unroll
      for (int i = 0; i < 2; i++){
        #pragma unroll
        for (int r = 0; r < 4; r++){
          const int s = rowA0 + wr * 32 + i * 16 + r4 + r;
          const float fc = ((s & 2047) == 2047) ? 0.f : softplus_f(acc1[i][j][r] + bv);
          const float fp = ((s & 2047) == 0)    ? 0.f : softplus_f(acc2[i][j][r] + bv);
          const size_t o = (size_t)s * 512 + col;
          const float mv = fmaxf(m32[o] + dt * (fp - fc), 1e-6f);
          m32[o] = mv;
          m16[o] = f2bf(mv);
        }
      }
    }
  }
}

// ---------------------------------------------------------------------------
extern "C" void kernel_launch(void* const* d_in, const int* in_sizes, int n_in,
                              void* d_out, int out_size, void* d_ws, size_t ws_size,
                              hipStream_t stream) {
  const int*   x      = (const int*)  d_in[0];
  const float* emb    = (const float*)d_in[1];
  const float* w_mass = (const float*)d_in[2];
  const float* b_mass = (const float*)d_in[3];
  const float* w_f1   = (const float*)d_in[4];
  const float* b_f1   = (const float*)d_in[5];
  const float* w_f2   = (const float*)d_in[6];
  const float* b_f2   = (const float*)d_in[7];
  const float* cfl    = (const float*)d_in[8];
  const float* w_dec  = (const float*)d_in[9];
  const float* b_dec  = (const float*)d_in[10];
  float* out = (float*)d_out;

  char* ws = (char*)d_ws;
  size_t off = 0;
  auto alloc = [&](size_t bytes) -> void* {
    void* p = ws + off;
    off += (bytes + 255) & ~(size_t)255;
    return p;
  };
  unsigned short* wTdec   = (unsigned short*)alloc((size_t)32000 * 512 * 2);
  unsigned short* eA      = (unsigned short*)alloc((size_t)4096 * 512 * 2);
  unsigned short* wTmass  = (unsigned short*)alloc((size_t)512 * 512 * 2);
  unsigned short* wTf1    = (unsigned short*)alloc((size_t)1024 * 512 * 2);
  unsigned short* wTf2    = (unsigned short*)alloc((size_t)512 * 512 * 2);
  float*          m32     = (float*)         alloc((size_t)4096 * 512 * 4);
  unsigned short* m16     = (unsigned short*)alloc((size_t)4097 * 512 * 2);  // +1 zero pad row
  unsigned short* act_pad = (unsigned short*)alloc((size_t)4104 * 512 * 2);  // row 0 zero pad

  hipFuncSetAttribute(reinterpret_cast<const void*>(&gemmDec),
                      hipFuncAttributeMaxDynamicSharedMemorySize, 147456);
  hipFuncSetAttribute(reinterpret_cast<const void*>(&fluxK<0>),
                      hipFuncAttributeMaxDynamicSharedMemorySize, 65536);
  hipFuncSetAttribute(reinterpret_cast<const void*>(&fluxK<1>),
                      hipFuncAttributeMaxDynamicSharedMemorySize, 65536);

  const dim3 b256(256);
  k_prep<<<19073, b256, 0, stream>>>(w_mass, w_f1, w_f2, w_dec, x, emb,
                                     wTmass, wTf1, wTf2, wTdec, eA,
                                     m16 + (size_t)4096 * 512, act_pad);

  // m = softplus(e @ w_mass + b_mass) + eps
  gemmP<128, 64, 2, 2, 8, 1><<<256, b256, 49152, stream>>>(eA, wTmass, b_mass, m32, m16, 512, 32);

  constexpr int FLUXA_LDS = (9 * 512 + 16 * 512) * 2 * 2;  // 51200 B
  constexpr int FLUXB_LDS = (9 * 512 +  8 * 512) * 2 * 2;  // 34816 B
  for (int it = 0; it < 3; ++it){
    fluxK<0><<<dim3(64, 8), b256, FLUXA_LDS, stream>>>(m16, wTf1, b_f1, nullptr,
                                                       nullptr, nullptr, act_pad);
    fluxK<1><<<dim3(64, 8), b256, FLUXB_LDS, stream>>>(act_pad, wTf2, b_f2, cfl,
                                                       m32, m16, nullptr);
  }

  // logits = m @ w_dec + b_dec -> f32 [4096, 32000]   (4000 WGs, 144 KiB LDS)
  gemmDec<<<4000, dim3(512), 147456, stream>>>(m16, wTdec, b_dec, out, 32000, 16);
}

// Round 6
// 410.016 us; speedup vs baseline: 1.5939x; 1.0113x over previous
//
#include <hip/hip_runtime.h>
#include <hip/hip_bf16.h>

#define DEV static __device__ __forceinline__

typedef __attribute__((ext_vector_type(4))) float f32x4;
typedef __attribute__((ext_vector_type(8))) short bf16x8;

DEV unsigned short f2bf(float x){
  __hip_bfloat16 h = __float2bfloat16(x);
  return __builtin_bit_cast(unsigned short, h);
}
DEV float b2f(unsigned short u){
  __hip_bfloat16 h = __builtin_bit_cast(__hip_bfloat16, u);
  return __bfloat162float(h);
}
DEV float softplus_f(float x){ return fmaxf(x, 0.f) + log1pf(expf(-fabsf(x))); }

DEV void gload16(const void* g, void* l){
  __builtin_amdgcn_global_load_lds((const __attribute__((address_space(1))) void*)g,
                                   (__attribute__((address_space(3))) void*)l, 16, 0, 0);
}

template<int N> DEV void waitcnt_vm(){
  if constexpr (N == 0) asm volatile("s_waitcnt vmcnt(0)" ::: "memory");
  else if constexpr (N == 5) asm volatile("s_waitcnt vmcnt(5)" ::: "memory");
  else if constexpr (N == 6) asm volatile("s_waitcnt vmcnt(6)" ::: "memory");
  else if constexpr (N == 7) asm volatile("s_waitcnt vmcnt(7)" ::: "memory");
  else if constexpr (N == 8) asm volatile("s_waitcnt vmcnt(8)" ::: "memory");
}

// ---------------------------------------------------------------------------
// Merged prep: [0,1024) four 512x512 transposes; [1024,17024) w_dec transpose;
// [17024,19072) gather (2 rows/block); 19072 pad-row zeroing.  256 thr.
__global__ void k_prep(const float* __restrict__ w_mass, const float* __restrict__ w_f1,
                       const float* __restrict__ w_f2, const float* __restrict__ w_dec,
                       const int* __restrict__ x, const float* __restrict__ emb,
                       unsigned short* __restrict__ wTmass, unsigned short* __restrict__ wTf1,
                       unsigned short* __restrict__ wTf2, unsigned short* __restrict__ wTdec,
                       unsigned short* __restrict__ eA,
                       unsigned short* __restrict__ m16_pad, unsigned short* __restrict__ act_pad0){
  __shared__ float t[32][33];
  const int b = blockIdx.x;
  const int tid = threadIdx.x;
  if (b >= 17024){
    const int local = b - 17024;
    if (local == 2048){
      if (tid < 128){
        const ushort4 z = {0, 0, 0, 0};
        ((ushort4*)m16_pad)[tid] = z;
        ((ushort4*)act_pad0)[tid] = z;
      }
      return;
    }
    const int row = local * 2 + (tid >> 7);
    const int c   = tid & 127;
    const int idx = x[row];
    const float4 v = ((const float4*)(emb + (size_t)idx * 512))[c];
    ushort4 o; o.x = f2bf(v.x); o.y = f2bf(v.y); o.z = f2bf(v.z); o.w = f2bf(v.w);
    ((ushort4*)(eA + (size_t)row * 512))[c] = o;
    return;
  }
  const float* in; unsigned short* out; int K, N, bx, by;
  if (b < 1024){
    const int z = b >> 8, idx = b & 255;
    bx = idx & 15; by = idx >> 4; K = 512; N = 512;
    switch (z){
      case 0:  in = w_mass;            out = wTmass;            break;
      case 1:  in = w_f1;              out = wTf1;              break;
      case 2:  in = w_f1 + 512 * 512;  out = wTf1 + 512 * 512;  break;
      default: in = w_f2;              out = wTf2;              break;
    }
  } else {
    const int local = b - 1024;
    bx = local % 1000; by = local / 1000; K = 512; N = 32000;
    in = w_dec; out = wTdec;
  }
  const int nt = bx * 32, kt = by * 32;
  const int r  = tid >> 3;
  const int c4 = (tid & 7) * 4;
  const float4 v = *(const float4*)(in + (size_t)(kt + r) * N + nt + c4);
  t[r][c4+0] = v.x; t[r][c4+1] = v.y; t[r][c4+2] = v.z; t[r][c4+3] = v.w;
  __syncthreads();
  ushort4 o;
  o.x = f2bf(t[c4+0][r]); o.y = f2bf(t[c4+1][r]);
  o.z = f2bf(t[c4+2][r]); o.w = f2bf(t[c4+3][r]);
  *(ushort4*)(out + (size_t)(nt + r) * K + kt + c4) = o;
}

// ---------------------------------------------------------------------------
// Pipelined GEMM (mass): C = A @ Bt^T; EPI 1: softplus(x+bias)+eps -> bf16 outBf.
template<int BM, int BN, int WM, int WN, int NT, int EPI>
__global__ __launch_bounds__(WM * WN * 64, 2)
void gemmP(const unsigned short* __restrict__ A, const unsigned short* __restrict__ Bt,
           const float* __restrict__ bias, unsigned short* __restrict__ outBf,
           int N, int nbx)
{
  constexpr int NW = WM * WN;
  constexpr int FA = BM / (WM * 16);
  constexpr int FB = BN / (WN * 16);
  constexpr int GA = BM / (8 * NW);
  constexpr int GB = BN / (8 * NW);
  constexpr int VC = GA + GB;
  constexpr int LA = BM * 64;
  constexpr int LB = BN * 64;
  constexpr int K  = NT * 64;

  extern __shared__ unsigned short lds[];
  const int tid  = threadIdx.x;
  const int lane = tid & 63;
  const int w    = tid >> 6;
  const int wr   = w / WN;
  const int wc   = w % WN;

  const int nwg = gridDim.x;
  const int cpx = nwg >> 3;
  const int swz = ((int)blockIdx.x & 7) * cpx + ((int)blockIdx.x >> 3);
  const int rowA0 = (swz % nbx) * BM;
  const int rowB0 = (swz / nbx) * BN;

  const int subr = lane >> 3;
  const int cc   = lane & 7;

  auto stage = [&](int kt, int buf){
    unsigned short* la = lds + buf * (LA + LB);
    unsigned short* lb = la + LA;
    const int k0 = kt * 64;
    #pragma unroll
    for (int i = 0; i < GA; i++){
      const int sub = w * GA + i;
      const int r   = sub * 8 + subr;
      const int cs  = cc ^ (r & 7);
      gload16(A + (size_t)(rowA0 + r) * K + k0 + cs * 8, la + sub * 512);
    }
    #pragma unroll
    for (int i = 0; i < GB; i++){
      const int sub = w * GB + i;
      const int r   = sub * 8 + subr;
      const int cs  = cc ^ (r & 7);
      gload16(Bt + (size_t)(rowB0 + r) * K + k0 + cs * 8, lb + sub * 512);
    }
  };

  f32x4 acc[FA][FB];
  const f32x4 z = {0.f, 0.f, 0.f, 0.f};
  #pragma unroll
  for (int i = 0; i < FA; i++)
    #pragma unroll
    for (int j = 0; j < FB; j++) acc[i][j] = z;

  stage(0, 0);
  stage(1, 1);
  waitcnt_vm<VC>();
  __builtin_amdgcn_s_barrier();
  __builtin_amdgcn_sched_barrier(0);

  #pragma unroll
  for (int t = 0; t < NT; ++t){
    const int cur = t & 1;
    const unsigned short* la = lds + cur * (LA + LB);
    const unsigned short* lb = la + LA;

    #pragma unroll
    for (int ks = 0; ks < 2; ks++){
      bf16x8 af[FA], bfr[FB];
      #pragma unroll
      for (int i = 0; i < FA; i++){
        const int ra = wr * (BM / WM) + i * 16 + (lane & 15);
        const int ka = (ks * 4 + (lane >> 4)) ^ (ra & 7);
        af[i] = *(const bf16x8*)(la + ra * 64 + ka * 8);
      }
      #pragma unroll
      for (int j = 0; j < FB; j++){
        const int rb = wc * (BN / WN) + j * 16 + (lane & 15);
        const int kb = (ks * 4 + (lane >> 4)) ^ (rb & 7);
        bfr[j] = *(const bf16x8*)(lb + rb * 64 + kb * 8);
      }
      if (ks == 1){
        asm volatile("s_waitcnt lgkmcnt(0)" ::: "memory");
        __builtin_amdgcn_sched_barrier(0);
        __builtin_amdgcn_s_barrier();
        __builtin_amdgcn_sched_barrier(0);
        if (t + 2 < NT) stage(t + 2, cur);
      }
      __builtin_amdgcn_s_setprio(1);
      #pragma unroll
      for (int i = 0; i < FA; i++)
        #pragma unroll
        for (int j = 0; j < FB; j++)
          acc[i][j] = __builtin_amdgcn_mfma_f32_16x16x32_bf16(af[i], bfr[j], acc[i][j], 0, 0, 0);
      __builtin_amdgcn_s_setprio(0);
    }

    if (t < NT - 1){
      if (t + 2 < NT) waitcnt_vm<VC>();
      else            waitcnt_vm<0>();
      __builtin_amdgcn_s_barrier();
      __builtin_amdgcn_sched_barrier(0);
    }
  }

  const int r4 = (lane >> 4) * 4;
  const int cl = lane & 15;
  #pragma unroll
  for (int j = 0; j < FB; j++){
    const int col = rowB0 + wc * (BN / WN) + j * 16 + cl;
    const float bv = bias[col];
    #pragma unroll
    for (int i = 0; i < FA; i++){
      const int row0 = rowA0 + wr * (BM / WM) + i * 16 + r4;
      #pragma unroll
      for (int r = 0; r < 4; r++){
        float v = softplus_f(acc[i][j][r] + bv) + 1e-6f;
        outBf[(size_t)(row0 + r) * N + col] = f2bf(v);
      }
    }
  }
}

// ---------------------------------------------------------------------------
// Decoder GEMM: 256x128 tile, 3 LDS buffers (144 KiB), 8 waves (4Mx2N),
// TWO PHASES PER K-TILE (ks=0 / ks=1) with JIT ds_reads, 3-load stage split per
// phase, counted vmcnt(6) once per tile (never drains mid-loop), setprio MFMA
// clusters.  Race ledger:
//   - stage at tile t targets buf[(t+2)%3]==buf[(t-1)%3]; its readers finished
//     before tile t-1's end barrier (lgkm precedes MFMAs precede barrier).
//   - vmcnt(6) at tile t end: 6 newest = tile t+2's loads; guarantees t+1
//     resident; barrier extends block-wide.
__global__ __launch_bounds__(512, 1)
void gemmDec(const unsigned short* __restrict__ A, const unsigned short* __restrict__ Bt,
             const float* __restrict__ bias, float* __restrict__ out, int N, int nbx)
{
  constexpr int BM = 256, BN = 128, NT = 8;
  constexpr int LA = BM * 64;              // shorts
  constexpr int LB = BN * 64;
  constexpr int BUF = LA + LB;             // 24576 shorts = 48 KiB
  constexpr int K = NT * 64;

  extern __shared__ unsigned short lds[];  // 3 * BUF
  const int tid  = threadIdx.x;
  const int lane = tid & 63;
  const int w    = tid >> 6;               // 0..7
  const int wr   = w >> 1;                 // 0..3
  const int wc   = w & 1;                  // 0..1

  const int nwg = gridDim.x;
  const int cpx = nwg >> 3;
  const int swz = ((int)blockIdx.x & 7) * cpx + ((int)blockIdx.x >> 3);
  const int rowA0 = (swz % nbx) * BM;
  const int rowB0 = (swz / nbx) * BN;

  const int subr = lane >> 3;
  const int cc   = lane & 7;

  // 3 loads/thread per call; half=0 covers A subs {w*4, w*4+1} + B sub {w*2},
  // half=1 covers A subs {w*4+2, w*4+3} + B sub {w*2+1}.
  auto stage3 = [&](int kt, int buf, int half){
    unsigned short* la = lds + buf * BUF;
    unsigned short* lb = la + LA;
    const int k0 = kt * 64;
    #pragma unroll
    for (int i = 0; i < 2; i++){
      const int sub = w * 4 + half * 2 + i;   // 0..31
      const int r   = sub * 8 + subr;         // 0..255
      const int cs  = cc ^ (r & 7);
      gload16(A + (size_t)(rowA0 + r) * K + k0 + cs * 8, la + sub * 512);
    }
    {
      const int sub = w * 2 + half;           // 0..15
      const int r   = sub * 8 + subr;         // 0..127
      const int cs  = cc ^ (r & 7);
      gload16(Bt + (size_t)(rowB0 + r) * K + k0 + cs * 8, lb + sub * 512);
    }
  };

  f32x4 acc[4][4];
  const f32x4 z = {0.f, 0.f, 0.f, 0.f};
  #pragma unroll
  for (int i = 0; i < 4; i++)
    #pragma unroll
    for (int j = 0; j < 4; j++) acc[i][j] = z;

  // prologue: tiles 0 and 1 fully staged (12 loads); tile 0 must land.
  stage3(0, 0, 0); stage3(0, 0, 1);
  stage3(1, 1, 0); stage3(1, 1, 1);
  waitcnt_vm<6>();
  __builtin_amdgcn_s_barrier();
  __builtin_amdgcn_sched_barrier(0);

  #pragma unroll
  for (int t = 0; t < NT; ++t){
    const int cur = t % 3;
    const unsigned short* la = lds + cur * BUF;
    const unsigned short* lb = la + LA;

    #pragma unroll
    for (int ks = 0; ks < 2; ks++){
      // stage 3 loads of tile t+2 (first or second half)
      if (t + 2 < NT) stage3(t + 2, (t + 2) % 3, ks);
      __builtin_amdgcn_sched_barrier(0);

      // JIT ds_reads for this ks only (8 x b128)
      bf16x8 af[4], bfr[4];
      #pragma unroll
      for (int i = 0; i < 4; i++){
        const int ra = wr * 64 + i * 16 + (lane & 15);
        const int ka = (ks * 4 + (lane >> 4)) ^ (ra & 7);
        af[i] = *(const bf16x8*)(la + ra * 64 + ka * 8);
      }
      #pragma unroll
      for (int j = 0; j < 4; j++){
        const int rb = wc * 64 + j * 16 + (lane & 15);
        const int kb = (ks * 4 + (lane >> 4)) ^ (rb & 7);
        bfr[j] = *(const bf16x8*)(lb + rb * 64 + kb * 8);
      }

      __builtin_amdgcn_s_setprio(1);
      #pragma unroll
      for (int i = 0; i < 4; i++)
        #pragma unroll
        for (int j = 0; j < 4; j++)
          acc[i][j] = __builtin_amdgcn_mfma_f32_16x16x32_bf16(af[i], bfr[j], acc[i][j], 0, 0, 0);
      __builtin_amdgcn_s_setprio(0);
      __builtin_amdgcn_sched_barrier(0);

      if (ks == 0){
        // mid-tile barrier: phase lockstep / role diversity
        __builtin_amdgcn_s_barrier();
        __builtin_amdgcn_sched_barrier(0);
      } else if (t < NT - 1){
        // end of tile: tile t+1 must be resident for next iter's ds_reads
        if (t + 2 < NT) waitcnt_vm<6>();   // 6 newest = tile t+2's loads
        else            waitcnt_vm<0>();
        __builtin_amdgcn_s_barrier();
        __builtin_amdgcn_sched_barrier(0);
      }
    }
  }

  const int r4 = (lane >> 4) * 4;
  const int cl = lane & 15;
  #pragma unroll
  for (int j = 0; j < 4; j++){
    const int col = rowB0 + wc * 64 + j * 16 + cl;
    const float bv = bias[col];
    #pragma unroll
    for (int i = 0; i < 4; i++){
      const int row0 = rowA0 + wr * 64 + i * 16 + r4;
      #pragma unroll
      for (int r = 0; r < 4; r++)
        out[(size_t)(row0 + r) * N + col] = acc[i][j][r] + bv;
    }
  }
}

// ---------------------------------------------------------------------------
// Fused flux kernels, 64x64 tile, dual accumulators via shifted-A fragments.
// MODE 0: act[s] = tanh(m[s]@W1a + m[s+1]@W1b + b1) -> act_pad[s+1].
// MODE 1: m = max(m + dt*(sp(F[s-1]) - sp(F[s])), eps), bf16 carry.
template<int MODE>
__global__ __launch_bounds__(256, 2)
void fluxK(const unsigned short* __restrict__ A, const unsigned short* __restrict__ Bt,
           const float* __restrict__ bias, const float* __restrict__ cfl,
           unsigned short* __restrict__ m16, unsigned short* __restrict__ act_pad)
{
  constexpr int ASUB = 9;
  constexpr int BSUB = (MODE == 0) ? 16 : 8;
  constexpr int GA = 3;
  constexpr int GB = (MODE == 0) ? 4 : 2;
  constexpr int VC = GA + GB;
  constexpr int ABUF = ASUB * 512;
  constexpr int BBUF = BSUB * 512;
  constexpr int BUFSZ = ABUF + BBUF;

  extern __shared__ unsigned short lds[];
  const int tid  = threadIdx.x;
  const int lane = tid & 63;
  const int w    = tid >> 6;
  const int wr   = w >> 1, wc = w & 1;
  const int rowA0 = blockIdx.x * 64;
  const int col0  = blockIdx.y * 64;
  const int subr = lane >> 3;
  const int cc   = lane & 7;

  auto stage = [&](int kt, int buf){
    unsigned short* la = lds + buf * BUFSZ;
    unsigned short* lb = la + ABUF;
    const int k0 = kt * 64;
    #pragma unroll
    for (int i = 0; i < GA; i++){
      const int si  = w * GA + i;
      const int sub = si > 8 ? 8 : si;
      const int r   = sub * 8 + subr;
      const int cs  = cc ^ subr;
      gload16(A + (size_t)(rowA0 + r) * 512 + k0 + cs * 8, la + sub * 512);
    }
    #pragma unroll
    for (int i = 0; i < GB; i++){
      const int sub = w * GB + i;
      int grow;
      if (MODE == 0) grow = (sub < 8) ? (col0 + sub * 8 + subr)
                                      : (512 + col0 + (sub - 8) * 8 + subr);
      else           grow = col0 + sub * 8 + subr;
      const int cs = cc ^ subr;
      gload16(Bt + (size_t)grow * 512 + k0 + cs * 8, lb + sub * 512);
    }
  };

  f32x4 acc1[2][2], acc2[2][2];
  const f32x4 z = {0.f, 0.f, 0.f, 0.f};
  #pragma unroll
  for (int i = 0; i < 2; i++)
    #pragma unroll
    for (int j = 0; j < 2; j++){ acc1[i][j] = z; acc2[i][j] = z; }

  stage(0, 0);
  stage(1, 1);
  waitcnt_vm<VC>();
  __builtin_amdgcn_s_barrier();
  __builtin_amdgcn_sched_barrier(0);

  #pragma unroll
  for (int t = 0; t < 8; ++t){
    const int cur = t & 1;
    const unsigned short* la = lds + cur * BUFSZ;
    const unsigned short* lb = la + ABUF;

    #pragma unroll
    for (int ks = 0; ks < 2; ks++){
      bf16x8 a0[2], a1[2], b0[2], b1v[2];
      #pragma unroll
      for (int i = 0; i < 2; i++){
        const int ra  = wr * 32 + i * 16 + (lane & 15);
        const int ka  = (ks * 4 + (lane >> 4)) ^ (ra & 7);
        a0[i] = *(const bf16x8*)(la + ra * 64 + ka * 8);
        const int ra1 = ra + 1;
        const int ka1 = (ks * 4 + (lane >> 4)) ^ (ra1 & 7);
        a1[i] = *(const bf16x8*)(la + ra1 * 64 + ka1 * 8);
      }
      #pragma unroll
      for (int j = 0; j < 2; j++){
        const int rb = wc * 32 + j * 16 + (lane & 15);
        const int kb = (ks * 4 + (lane >> 4)) ^ (rb & 7);
        b0[j] = *(const bf16x8*)(lb + rb * 64 + kb * 8);
        if (MODE == 0) b1v[j] = *(const bf16x8*)(lb + (64 + rb) * 64 + kb * 8);
      }
      if (ks == 1){
        asm volatile("s_waitcnt lgkmcnt(0)" ::: "memory");
        __builtin_amdgcn_sched_barrier(0);
        __builtin_amdgcn_s_barrier();
        __builtin_amdgcn_sched_barrier(0);
        if (t + 2 < 8) stage(t + 2, cur);
      }
      __builtin_amdgcn_s_setprio(1);
      #pragma unroll
      for (int i = 0; i < 2; i++)
        #pragma unroll
        for (int j = 0; j < 2; j++){
          if (MODE == 0){
            acc1[i][j] = __builtin_amdgcn_mfma_f32_16x16x32_bf16(a0[i], b0[j],  acc1[i][j], 0, 0, 0);
            acc2[i][j] = __builtin_amdgcn_mfma_f32_16x16x32_bf16(a1[i], b1v[j], acc2[i][j], 0, 0, 0);
          } else {
            acc1[i][j] = __builtin_amdgcn_mfma_f32_16x16x32_bf16(a1[i], b0[j], acc1[i][j], 0, 0, 0); // F[s]
            acc2[i][j] = __builtin_amdgcn_mfma_f32_16x16x32_bf16(a0[i], b0[j], acc2[i][j], 0, 0, 0); // F[s-1]
          }
        }
      __builtin_amdgcn_s_setprio(0);
    }

    if (t < 7){
      if (t + 2 < 8) waitcnt_vm<VC>();
      else           waitcnt_vm<0>();
      __builtin_amdgcn_s_barrier();
      __builtin_amdgcn_sched_barrier(0);
    }
  }

  const int r4 = (lane >> 4) * 4;
  const int cl = lane & 15;
  if (MODE == 0){
    #pragma unroll
    for (int j = 0; j < 2; j++){
      const int col = col0 + wc * 32 + j * 16 + cl;
      const float bv = bias[col];
      #pragma unroll
      for (int i = 0; i < 2; i++){
        #pragma unroll
        for (int r = 0; r < 4; r++){
          const int s = rowA0 + wr * 32 + i * 16 + r4 + r;
          const float v = tanhf(acc1[i][j][r] + acc2[i][j][r] + bv);
          act_pad[(size_t)(s + 1) * 512 + col] = ((s & 2047) == 2047) ? 0 : f2bf(v);
        }
      }
    }
  } else {
    const float dt = 1.f / (1.f + expf(-cfl[0]));
    #pragma unroll
    for (int j = 0; j < 2; j++){
      const int col = col0 + wc * 32 + j * 16 + cl;
      const float bv = bias[col];
      #pragma unroll
      for (int i = 0; i < 2; i++){
        #pragma unroll
        for (int r = 0; r < 4; r++){
          const int s = rowA0 + wr * 32 + i * 16 + r4 + r;
          const float fc = ((s & 2047) == 2047) ? 0.f : softplus_f(acc1[i][j][r] + bv);
          const float fp = ((s & 2047) == 0)    ? 0.f : softplus_f(acc2[i][j][r] + bv);
          const size_t o = (size_t)s * 512 + col;
          const float mv = fmaxf(b2f(m16[o]) + dt * (fp - fc), 1e-6f);
          m16[o] = f2bf(mv);
        }
      }
    }
  }
}

// ---------------------------------------------------------------------------
extern "C" void kernel_launch(void* const* d_in, const int* in_sizes, int n_in,
                              void* d_out, int out_size, void* d_ws, size_t ws_size,
                              hipStream_t stream) {
  const int*   x      = (const int*)  d_in[0];
  const float* emb    = (const float*)d_in[1];
  const float* w_mass = (const float*)d_in[2];
  const float* b_mass = (const float*)d_in[3];
  const float* w_f1   = (const float*)d_in[4];
  const float* b_f1   = (const float*)d_in[5];
  const float* w_f2   = (const float*)d_in[6];
  const float* b_f2   = (const float*)d_in[7];
  const float* cfl    = (const float*)d_in[8];
  const float* w_dec  = (const float*)d_in[9];
  const float* b_dec  = (const float*)d_in[10];
  float* out = (float*)d_out;

  char* ws = (char*)d_ws;
  size_t off = 0;
  auto alloc = [&](size_t bytes) -> void* {
    void* p = ws + off;
    off += (bytes + 255) & ~(size_t)255;
    return p;
  };
  unsigned short* wTdec   = (unsigned short*)alloc((size_t)32000 * 512 * 2);
  unsigned short* eA      = (unsigned short*)alloc((size_t)4096 * 512 * 2);
  unsigned short* wTmass  = (unsigned short*)alloc((size_t)512 * 512 * 2);
  unsigned short* wTf1    = (unsigned short*)alloc((size_t)1024 * 512 * 2);
  unsigned short* wTf2    = (unsigned short*)alloc((size_t)512 * 512 * 2);
  unsigned short* m16     = (unsigned short*)alloc((size_t)4097 * 512 * 2);  // +1 zero pad row
  unsigned short* act_pad = (unsigned short*)alloc((size_t)4104 * 512 * 2);  // row 0 zero pad

  hipFuncSetAttribute(reinterpret_cast<const void*>(&gemmDec),
                      hipFuncAttributeMaxDynamicSharedMemorySize, 147456);
  hipFuncSetAttribute(reinterpret_cast<const void*>(&fluxK<0>),
                      hipFuncAttributeMaxDynamicSharedMemorySize, 65536);
  hipFuncSetAttribute(reinterpret_cast<const void*>(&fluxK<1>),
                      hipFuncAttributeMaxDynamicSharedMemorySize, 65536);

  const dim3 b256(256);
  k_prep<<<19073, b256, 0, stream>>>(w_mass, w_f1, w_f2, w_dec, x, emb,
                                     wTmass, wTf1, wTf2, wTdec, eA,
                                     m16 + (size_t)4096 * 512, act_pad);

  // m = softplus(e @ w_mass + b_mass) + eps  (bf16 carry)
  gemmP<128, 64, 2, 2, 8, 1><<<256, b256, 49152, stream>>>(eA, wTmass, b_mass, m16, 512, 32);

  constexpr int FLUXA_LDS = (9 * 512 + 16 * 512) * 2 * 2;  // 51200 B
  constexpr int FLUXB_LDS = (9 * 512 +  8 * 512) * 2 * 2;  // 34816 B
  for (int it = 0; it < 3; ++it){
    fluxK<0><<<dim3(64, 8), b256, FLUXA_LDS, stream>>>(m16, wTf1, b_f1, nullptr,
                                                       nullptr, act_pad);
    fluxK<1><<<dim3(64, 8), b256, FLUXB_LDS, stream>>>(act_pad, wTf2, b_f2, cfl,
                                                       m16, nullptr);
  }

  // logits = m @ w_dec + b_dec -> f32 [4096, 32000]  (4000 WGs, 144 KiB LDS)
  gemmDec<<<4000, dim3(512), 147456, stream>>>(m16, wTdec, b_dec, out, 32000, 16);
}